// Round 3
// baseline (787.253 us; speedup 1.0000x reference)
//
#include <hip/hip_runtime.h>
#include <math.h>

typedef _Float16 f16;
typedef _Float16 f16x8 __attribute__((ext_vector_type(8)));
typedef float    f32x4 __attribute__((ext_vector_type(4)));

#define DIMK 4096
#define HIDN 1024
#define NTOK 16384
#define SLEN 4096
#define NBATCH 4
#define KSEL 2048
#define NPART 16

#define F16_MIN_NORMAL 6.1035156e-5f
#define LO_SCALE 2048.0f
#define INV_LO_SCALE (1.0f/2048.0f)

// ---------------------------------------------------------------------------
// helpers
// ---------------------------------------------------------------------------
__device__ __forceinline__ void load_lds16(const void* g, void* l) {
    __builtin_amdgcn_global_load_lds(
        (const __attribute__((address_space(1))) unsigned int*)g,
        (__attribute__((address_space(3))) unsigned int*)l, 16, 0, 0);
}
// XOR swizzle of the 16B slot within a 64B LDS row: 2-way-max bank conflicts.
__device__ __forceinline__ int swzf(int row) { return ((row >> 1) & 3) << 4; }

// split v = hi + lo*2^-11 with hi,lo f16, hi clamped out of subnormal range
// (flush-robust) and lo pre-scaled into normal range.
__device__ __forceinline__ void split_f16(float v, f16& hi, f16& lo) {
    f16 h = (f16)v;
    float hf = (float)h;
    if (fabsf(hf) < F16_MIN_NORMAL) { h = (f16)0.0f; hf = 0.0f; }
    hi = h;
    lo = (f16)((v - hf) * LO_SCALE);
}

// ---------------------------------------------------------------------------
// Kernel A: convert x (fp32) -> xhi, xlo (f16, lo pre-scaled)
// ---------------------------------------------------------------------------
__global__ __launch_bounds__(256) void conv_x_kernel(
    const float* x, f16* xhi, f16* xlo)
{
    const size_t total = (size_t)NTOK * DIMK / 4;   // float4 groups
    const size_t stride = (size_t)gridDim.x * blockDim.x;
    for (size_t idx = (size_t)blockIdx.x * blockDim.x + threadIdx.x;
         idx < total; idx += stride) {
        const float4 v = ((const float4*)x)[idx];
        f16 h0, h1, h2, h3, l0, l1, l2, l3;
        split_f16(v.x, h0, l0);
        split_f16(v.y, h1, l1);
        split_f16(v.z, h2, l2);
        split_f16(v.w, h3, l3);
        ushort4 hp, lp;
        hp.x = __builtin_bit_cast(unsigned short, h0);
        hp.y = __builtin_bit_cast(unsigned short, h1);
        hp.z = __builtin_bit_cast(unsigned short, h2);
        hp.w = __builtin_bit_cast(unsigned short, h3);
        lp.x = __builtin_bit_cast(unsigned short, l0);
        lp.y = __builtin_bit_cast(unsigned short, l1);
        lp.z = __builtin_bit_cast(unsigned short, l2);
        lp.w = __builtin_bit_cast(unsigned short, l3);
        ((ushort4*)xhi)[idx] = hp;
        ((ushort4*)xlo)[idx] = lp;
    }
}

// ---------------------------------------------------------------------------
// Kernel B: transpose + convert w1 [DIMK][HIDN] fp32 -> w1t hi/lo [HIDN][DIMK] f16
// 64x64 tiles via LDS.
// ---------------------------------------------------------------------------
__global__ __launch_bounds__(256) void conv_w1_kernel(
    const float* w1, f16* wthi, f16* wtlo)
{
    __shared__ float t[64][65];
    const int bx = blockIdx.x & 15;        // n-tile (HIDN/64 = 16)
    const int by = blockIdx.x >> 4;        // k-tile (DIMK/64 = 64)
    #pragma unroll
    for (int i = 0; i < 16; ++i) {
        const int e = threadIdx.x + i * 256;
        const int r = e >> 6, c = e & 63;
        t[r][c] = w1[(size_t)(by * 64 + r) * HIDN + bx * 64 + c];
    }
    __syncthreads();
    #pragma unroll
    for (int i = 0; i < 16; ++i) {
        const int e = threadIdx.x + i * 256;
        const int nrow = e >> 6, kcol = e & 63;
        f16 h, l;
        split_f16(t[kcol][nrow], h, l);
        const size_t o = (size_t)(bx * 64 + nrow) * DIMK + by * 64 + kcol;
        wthi[o] = h;
        wtlo[o] = l;
    }
}

// ---------------------------------------------------------------------------
// Kernel C: 3-pass f16 MFMA GEMM + fused relu/w2 epilogue -> score partials.
// H = xhi*whi*2048 + xhi*wlo_s + xlo_s*whi   (all at 2^11 scale), h = H/2048.
// 128x128 tile, BK=32, 4 waves (2x2), 16x16x32 MFMA, 4x4 frags/wave.
// partials[slot][token], slot = nblk*2 + wc  (16 slots), summed by router.
// ---------------------------------------------------------------------------
#define GBM 128
#define GBN 128
#define GBK 32

__global__ __launch_bounds__(256) void mod_mfma_kernel(
    const f16* xhi, const f16* xlo, const f16* wthi, const f16* wtlo,
    const float* b1, const float* w2, float* partials)
{
    __shared__ __align__(16) f16 Alds[GBM * GBK];   // 8 KB
    __shared__ __align__(16) f16 Blds[GBN * GBK];   // 8 KB

    const int tid  = threadIdx.x;
    const int lane = tid & 63;
    const int wid  = tid >> 6;
    const int wr   = wid >> 1;
    const int wc   = wid & 1;

    // XCD-chunked bijective swizzle (1024 blocks % 8 == 0): each XCD gets a
    // contiguous mblk range; n varies fastest -> A panels L2-resident per XCD.
    const int bid  = blockIdx.x;
    const int v    = (bid & 7) * 128 + (bid >> 3);
    const int nblk = v & 7;
    const int mblk = v >> 3;
    const int tokBase = mblk * GBM;
    const int nBase   = nblk * GBN;

    // staging constants: wave wid fills chunks wid*2+{0,1} (1KB each) of A and B
    int row[2], sof[2];
    #pragma unroll
    for (int i = 0; i < 2; ++i) {
        const int r = (wid * 2 + i) * 16 + (lane >> 2);
        row[i] = r;
        sof[i] = ((lane & 3) << 4) ^ swzf(r);   // pre-swizzled source slot
    }

    // fragment-read byte offsets (constant per thread)
    int aoff[4], boff[4];
    #pragma unroll
    for (int m = 0; m < 4; ++m) {
        const int r = wr * 64 + m * 16 + (lane & 15);
        aoff[m] = r * 64 + (((lane >> 4) << 4) ^ swzf(r));
        const int c = wc * 64 + m * 16 + (lane & 15);
        boff[m] = c * 64 + (((lane >> 4) << 4) ^ swzf(c));
    }

    f32x4 acc[4][4];
    #pragma unroll
    for (int m = 0; m < 4; ++m)
        #pragma unroll
        for (int n = 0; n < 4; ++n)
            #pragma unroll
            for (int j = 0; j < 4; ++j) acc[m][n][j] = 0.0f;

    for (int pass = 0; pass < 3; ++pass) {
        const f16* Aq = (pass == 2) ? xlo : xhi;
        const f16* Bq = (pass == 1) ? wtlo : wthi;

        for (int k0 = 0; k0 < DIMK; k0 += GBK) {
            #pragma unroll
            for (int i = 0; i < 2; ++i) {
                load_lds16((const char*)Aq + ((size_t)(tokBase + row[i]) * DIMK + k0) * 2 + sof[i],
                           (char*)Alds + (wid * 2 + i) * 1024);
                load_lds16((const char*)Bq + ((size_t)(nBase + row[i]) * DIMK + k0) * 2 + sof[i],
                           (char*)Blds + (wid * 2 + i) * 1024);
            }
            __syncthreads();   // drains vmcnt (global_load_lds) + lgkm

            f16x8 af[4], bf[4];
            #pragma unroll
            for (int m = 0; m < 4; ++m)
                af[m] = *(const f16x8*)((const char*)Alds + aoff[m]);
            #pragma unroll
            for (int n = 0; n < 4; ++n)
                bf[n] = *(const f16x8*)((const char*)Blds + boff[n]);

            #pragma unroll
            for (int m = 0; m < 4; ++m)
                #pragma unroll
                for (int n = 0; n < 4; ++n)
                    acc[m][n] = __builtin_amdgcn_mfma_f32_16x16x32_f16(
                        af[m], bf[n], acc[m][n], 0, 0, 0);
            __syncthreads();   // reads done before next tile overwrites LDS
        }

        if (pass == 0) {
            // bring hi*hi to the 2^11 scale (exact pow2 multiply)
            #pragma unroll
            for (int m = 0; m < 4; ++m)
                #pragma unroll
                for (int n = 0; n < 4; ++n)
                    #pragma unroll
                    for (int j = 0; j < 4; ++j) acc[m][n][j] *= LO_SCALE;
        }
    }

    // epilogue: h = acc/2048 + b1; score partial = sum relu(h)*w2 over this
    // wave's 64 cols. C/D layout (m89-verified): col = lane&15,
    // row = (lane>>4)*4 + j within each 16x16 fragment.
    float rp[4][4];
    #pragma unroll
    for (int m = 0; m < 4; ++m)
        #pragma unroll
        for (int j = 0; j < 4; ++j) rp[m][j] = 0.0f;

    #pragma unroll
    for (int n = 0; n < 4; ++n) {
        const int col = nBase + wc * 64 + n * 16 + (lane & 15);
        const float wv = w2[col];
        const float bb = b1[col];
        #pragma unroll
        for (int m = 0; m < 4; ++m)
            #pragma unroll
            for (int j = 0; j < 4; ++j) {
                float h = fmaf(acc[m][n][j], INV_LO_SCALE, bb);
                h = fmaxf(h, 0.0f);
                rp[m][j] = fmaf(h, wv, rp[m][j]);
            }
    }
    // reduce across the 16 lanes of each quarter (distinct cols, same rows)
    #pragma unroll
    for (int off = 1; off < 16; off <<= 1)
        #pragma unroll
        for (int m = 0; m < 4; ++m)
            #pragma unroll
            for (int j = 0; j < 4; ++j)
                rp[m][j] += __shfl_xor(rp[m][j], off, 64);

    if ((lane & 15) == 0) {
        const int q = lane >> 4;
        const int slot = nblk * 2 + wc;
        float* pdst = partials + (size_t)slot * NTOK + tokBase + wr * 64 + q * 4;
        #pragma unroll
        for (int m = 0; m < 4; ++m)
            #pragma unroll
            for (int j = 0; j < 4; ++j)
                pdst[m * 16 + j] = rp[m][j];
    }
}

// ---------------------------------------------------------------------------
// Kernel D: router (validated round-1 semantics), scores = sum of 16 partials
// + b2. rw[b, p_m] = soft[m], p_m = m-th smallest selected index, soft[m] =
// m-th largest softmax value. Bitonic sort desc; threshold = s[2047];
// tie-safe lowest-index-first; rank via ping-pong prefix scan.
// ---------------------------------------------------------------------------
__global__ __launch_bounds__(1024) void mod_route_part_kernel(
    const float* partials, const float* b2,
    float* mask_out, float* rw_out)
{
    __shared__ float s[SLEN];
    __shared__ int   sg[2][1024];
    __shared__ int   se[2][1024];
    __shared__ float red[1024];

    const int b   = blockIdx.x;
    const int tid = threadIdx.x;
    const int base = tid * 4;
    const float bias2 = b2[0];

    // all global reads up front, before the first barrier
    float og[4];
    #pragma unroll
    for (int u = 0; u < 4; ++u) {
        const size_t tok = (size_t)b * SLEN + base + u;
        float sum = bias2;
        #pragma unroll
        for (int p = 0; p < NPART; ++p) sum += partials[(size_t)p * NTOK + tok];
        og[u] = sum;
        s[base + u] = sum;
    }
    __syncthreads();

    // bitonic sort, descending
    for (int k = 2; k <= SLEN; k <<= 1) {
        for (int j = k >> 1; j > 0; j >>= 1) {
            for (int i = tid; i < SLEN; i += 1024) {
                const int ixj = i ^ j;
                if (ixj > i) {
                    const float a = s[i];
                    const float c = s[ixj];
                    const bool descRegion = ((i & k) == 0);
                    if (descRegion ? (a < c) : (a > c)) { s[i] = c; s[ixj] = a; }
                }
            }
            __syncthreads();
        }
    }

    const float maxv      = s[0];
    const float threshold = s[KSEL - 1];

    float part = 0.f;
    for (int i = tid; i < KSEL; i += 1024) part += expf(s[i] - maxv);
    red[tid] = part;
    __syncthreads();
    for (int off = 512; off > 0; off >>= 1) {
        if (tid < off) red[tid] += red[tid + off];
        __syncthreads();
    }
    const float sumexp = red[0];
    __syncthreads();

    int gcnt = 0, ecnt = 0;
    #pragma unroll
    for (int u = 0; u < 4; ++u) {
        gcnt += (og[u] > threshold);
        ecnt += (og[u] == threshold);
    }

    int cur = 0;
    sg[0][tid] = gcnt;
    se[0][tid] = ecnt;
    __syncthreads();
    for (int off = 1; off < 1024; off <<= 1) {
        const int nxt = cur ^ 1;
        int vg = sg[cur][tid];
        int ve = se[cur][tid];
        if (tid >= off) { vg += sg[cur][tid - off]; ve += se[cur][tid - off]; }
        sg[nxt][tid] = vg;
        se[nxt][tid] = ve;
        __syncthreads();
        cur = nxt;
    }
    const int total_gt = sg[cur][1023];
    const int R = KSEL - total_gt;
    int pgi = sg[cur][tid] - gcnt;
    int pei = se[cur][tid] - ecnt;

    const float inv_sum = 1.0f / sumexp;
    #pragma unroll
    for (int u = 0; u < 4; ++u) {
        const bool isg = og[u] > threshold;
        const bool ise = og[u] == threshold;
        const bool sel = isg || (ise && pei < R);
        float rwv = 0.f;
        if (sel) {
            const int rank = pgi + (pei < R ? pei : R);
            rwv = expf(s[rank] - maxv) * inv_sum;
        }
        const size_t oi = (size_t)b * SLEN + base + u;
        mask_out[oi] = sel ? 1.0f : 0.0f;
        rw_out[oi]   = rwv;
        pgi += isg;
        pei += ise;
    }
}

// ---------------------------------------------------------------------------
// Fallback path (ws too small): validated fp32 VALU scorer + scores-in-rw_out
// ---------------------------------------------------------------------------
#define BM 64
#define BN 256
#define BK 32
#define THREADS 512

__global__ __launch_bounds__(THREADS) void mod_score_kernel(
    const float* x, const float* w1, const float* b1,
    const float* w2, const float* b2, float* scores)
{
    __shared__ float Xs[BK][BM + 4];
    __shared__ float Ws[BK][BN];

    const int tid = threadIdx.x;
    const int tx = tid & 31;
    const int ty = tid >> 5;
    const int tokBase = blockIdx.x * BM;

    float sp[4] = {0.f, 0.f, 0.f, 0.f};
    const float bias2 = b2[0];

    for (int hc = 0; hc < HIDN; hc += BN) {
        float acc[4][8];
        #pragma unroll
        for (int m = 0; m < 4; ++m)
            #pragma unroll
            for (int n = 0; n < 8; ++n) acc[m][n] = 0.f;

        for (int k0 = 0; k0 < DIMK; k0 += BK) {
            {
                const int r  = tid >> 3;
                const int c4 = tid & 7;
                const float4 vv = *(const float4*)(x + (size_t)(tokBase + r) * DIMK + k0 + c4 * 4);
                Xs[c4 * 4 + 0][r] = vv.x;
                Xs[c4 * 4 + 1][r] = vv.y;
                Xs[c4 * 4 + 2][r] = vv.z;
                Xs[c4 * 4 + 3][r] = vv.w;
            }
            #pragma unroll
            for (int i = 0; i < 4; ++i) {
                const int idx = tid + i * THREADS;
                const int r   = idx >> 6;
                const int c4  = idx & 63;
                const float4 vv = *(const float4*)(w1 + (size_t)(k0 + r) * HIDN + hc + c4 * 4);
                *(float4*)&Ws[r][c4 * 4] = vv;
            }
            __syncthreads();

            #pragma unroll 8
            for (int k = 0; k < BK; ++k) {
                const float4 xv = *(const float4*)&Xs[k][ty * 4];
                const float4 wa = *(const float4*)&Ws[k][tx * 4];
                const float4 wb = *(const float4*)&Ws[k][128 + tx * 4];
                const float xm[4] = {xv.x, xv.y, xv.z, xv.w};
                const float wn[8] = {wa.x, wa.y, wa.z, wa.w, wb.x, wb.y, wb.z, wb.w};
                #pragma unroll
                for (int m = 0; m < 4; ++m)
                    #pragma unroll
                    for (int n = 0; n < 8; ++n)
                        acc[m][n] = fmaf(xm[m], wn[n], acc[m][n]);
            }
            __syncthreads();
        }

        #pragma unroll
        for (int half = 0; half < 2; ++half) {
            #pragma unroll
            for (int n = 0; n < 4; ++n) {
                const int h = hc + half * 128 + tx * 4 + n;
                const float wv = w2[h];
                const float bb = b1[h];
                #pragma unroll
                for (int m = 0; m < 4; ++m) {
                    float hv = acc[m][half * 4 + n] + bb;
                    hv = fmaxf(hv, 0.f);
                    sp[m] = fmaf(hv, wv, sp[m]);
                }
            }
        }
    }

    #pragma unroll
    for (int off = 1; off < 32; off <<= 1) {
        #pragma unroll
        for (int m = 0; m < 4; ++m) sp[m] += __shfl_xor(sp[m], off, 64);
    }
    if (tx == 0) {
        #pragma unroll
        for (int m = 0; m < 4; ++m)
            scores[tokBase + ty * 4 + m] = sp[m] + bias2;
    }
}

__global__ __launch_bounds__(1024) void mod_route_kernel(
    const float* scores, float* mask_out, float* rw_out)
{
    __shared__ float s[SLEN];
    __shared__ int   sg[2][1024];
    __shared__ int   se[2][1024];
    __shared__ float red[1024];

    const int b   = blockIdx.x;
    const int tid = threadIdx.x;
    const float* rowp = scores + (size_t)b * SLEN;
    const int base = tid * 4;

    const float4 ov = *(const float4*)(rowp + base);
    float og[4] = {ov.x, ov.y, ov.z, ov.w};
    s[base + 0] = ov.x;
    s[base + 1] = ov.y;
    s[base + 2] = ov.z;
    s[base + 3] = ov.w;
    __syncthreads();

    for (int k = 2; k <= SLEN; k <<= 1) {
        for (int j = k >> 1; j > 0; j >>= 1) {
            for (int i = tid; i < SLEN; i += 1024) {
                const int ixj = i ^ j;
                if (ixj > i) {
                    const float a = s[i];
                    const float c = s[ixj];
                    const bool descRegion = ((i & k) == 0);
                    if (descRegion ? (a < c) : (a > c)) { s[i] = c; s[ixj] = a; }
                }
            }
            __syncthreads();
        }
    }

    const float maxv      = s[0];
    const float threshold = s[KSEL - 1];

    float part = 0.f;
    for (int i = tid; i < KSEL; i += 1024) part += expf(s[i] - maxv);
    red[tid] = part;
    __syncthreads();
    for (int off = 512; off > 0; off >>= 1) {
        if (tid < off) red[tid] += red[tid + off];
        __syncthreads();
    }
    const float sumexp = red[0];
    __syncthreads();

    int gcnt = 0, ecnt = 0;
    #pragma unroll
    for (int u = 0; u < 4; ++u) {
        gcnt += (og[u] > threshold);
        ecnt += (og[u] == threshold);
    }

    int cur = 0;
    sg[0][tid] = gcnt;
    se[0][tid] = ecnt;
    __syncthreads();
    for (int off = 1; off < 1024; off <<= 1) {
        const int nxt = cur ^ 1;
        int vg = sg[cur][tid];
        int ve = se[cur][tid];
        if (tid >= off) { vg += sg[cur][tid - off]; ve += se[cur][tid - off]; }
        sg[nxt][tid] = vg;
        se[nxt][tid] = ve;
        __syncthreads();
        cur = nxt;
    }
    const int total_gt = sg[cur][1023];
    const int R = KSEL - total_gt;
    int pgi = sg[cur][tid] - gcnt;
    int pei = se[cur][tid] - ecnt;

    const float inv_sum = 1.0f / sumexp;
    #pragma unroll
    for (int u = 0; u < 4; ++u) {
        const bool isg = og[u] > threshold;
        const bool ise = og[u] == threshold;
        const bool sel = isg || (ise && pei < R);
        float rwv = 0.f;
        if (sel) {
            const int rank = pgi + (pei < R ? pei : R);
            rwv = expf(s[rank] - maxv) * inv_sum;
        }
        const size_t oi = (size_t)b * SLEN + base + u;
        mask_out[oi] = sel ? 1.0f : 0.0f;
        rw_out[oi]   = rwv;
        pgi += isg;
        pei += ise;
    }
}

// ---------------------------------------------------------------------------
extern "C" void kernel_launch(void* const* d_in, const int* in_sizes, int n_in,
                              void* d_out, int out_size, void* d_ws, size_t ws_size,
                              hipStream_t stream) {
    const float* x  = (const float*)d_in[0];
    const float* w1 = (const float*)d_in[1];
    const float* b1 = (const float*)d_in[2];
    const float* w2 = (const float*)d_in[3];
    const float* b2 = (const float*)d_in[4];

    float* out      = (float*)d_out;
    float* mask_out = out;            // [4, 4096]
    float* rw_out   = out + NTOK;     // [4, 4096]

    const size_t partials_b = (size_t)NPART * NTOK * 4;          // 1 MB
    const size_t xsplit_b   = (size_t)NTOK * DIMK * 2;           // 134 MB each
    const size_t wsplit_b   = (size_t)HIDN * DIMK * 2;           // 8 MB each
    const size_t needed     = partials_b + 2 * xsplit_b + 2 * wsplit_b;

    if (ws_size >= needed) {
        char* wsb = (char*)d_ws;
        float* partials = (float*)wsb;
        f16* xhi  = (f16*)(wsb + partials_b);
        f16* xlo  = xhi + (size_t)NTOK * DIMK;
        f16* wthi = (f16*)(wsb + partials_b + 2 * xsplit_b);
        f16* wtlo = wthi + (size_t)HIDN * DIMK;

        conv_x_kernel<<<2048, 256, 0, stream>>>(x, xhi, xlo);
        conv_w1_kernel<<<1024, 256, 0, stream>>>(w1, wthi, wtlo);
        mod_mfma_kernel<<<1024, 256, 0, stream>>>(xhi, xlo, wthi, wtlo, b1, w2, partials);
        mod_route_part_kernel<<<NBATCH, 1024, 0, stream>>>(partials, b2, mask_out, rw_out);
    } else {
        // fallback: validated fp32 path, scores staged in rw_out region
        float* scores = (ws_size >= (size_t)NTOK * sizeof(float)) ? (float*)d_ws : rw_out;
        mod_score_kernel<<<NTOK / BM, THREADS, 0, stream>>>(x, w1, b1, w2, b2, scores);
        mod_route_kernel<<<NBATCH, 1024, 0, stream>>>(scores, mask_out, rw_out);
    }
}

// Round 5
// 609.929 us; speedup vs baseline: 1.2907x; 1.2907x over previous
//
#include <hip/hip_runtime.h>
#include <math.h>

typedef _Float16 f16;
typedef _Float16 f16x8 __attribute__((ext_vector_type(8)));
typedef float    f32x4 __attribute__((ext_vector_type(4)));

#define DIMK 4096
#define HIDN 1024
#define NTOK 16384
#define SLEN 4096
#define NBATCH 4
#define KSEL 2048
#define NPART 16

#define F16_MIN_NORMAL 6.1035156e-5f
#define LO_SCALE 2048.0f
#define INV_LO_SCALE (1.0f/2048.0f)

// ---------------------------------------------------------------------------
// helpers
// ---------------------------------------------------------------------------
__device__ __forceinline__ void load_lds16(const void* g, void* l) {
    __builtin_amdgcn_global_load_lds(
        (const __attribute__((address_space(1))) unsigned int*)g,
        (__attribute__((address_space(3))) unsigned int*)l, 16, 0, 0);
}
// XOR swizzle of the 16B slot within a 64B LDS row: 2-way-max bank conflicts.
__device__ __forceinline__ int swzf(int row) { return ((row >> 1) & 3) << 4; }

// split v = hi + lo*2^-11 with hi,lo f16, hi clamped out of subnormal range
// (flush-robust) and lo pre-scaled into normal range.
__device__ __forceinline__ void split_f16(float v, f16& hi, f16& lo) {
    f16 h = (f16)v;
    float hf = (float)h;
    if (fabsf(hf) < F16_MIN_NORMAL) { h = (f16)0.0f; hf = 0.0f; }
    hi = h;
    lo = (f16)((v - hf) * LO_SCALE);
}

// ---------------------------------------------------------------------------
// Kernel A: convert x (fp32) -> xhi, xlo (f16, lo pre-scaled)
// ---------------------------------------------------------------------------
__global__ __launch_bounds__(256) void conv_x_kernel(
    const float* x, f16* xhi, f16* xlo)
{
    const size_t total = (size_t)NTOK * DIMK / 4;   // float4 groups
    const size_t stride = (size_t)gridDim.x * blockDim.x;
    for (size_t idx = (size_t)blockIdx.x * blockDim.x + threadIdx.x;
         idx < total; idx += stride) {
        const float4 v = ((const float4*)x)[idx];
        f16 h0, h1, h2, h3, l0, l1, l2, l3;
        split_f16(v.x, h0, l0);
        split_f16(v.y, h1, l1);
        split_f16(v.z, h2, l2);
        split_f16(v.w, h3, l3);
        ushort4 hp, lp;
        hp.x = __builtin_bit_cast(unsigned short, h0);
        hp.y = __builtin_bit_cast(unsigned short, h1);
        hp.z = __builtin_bit_cast(unsigned short, h2);
        hp.w = __builtin_bit_cast(unsigned short, h3);
        lp.x = __builtin_bit_cast(unsigned short, l0);
        lp.y = __builtin_bit_cast(unsigned short, l1);
        lp.z = __builtin_bit_cast(unsigned short, l2);
        lp.w = __builtin_bit_cast(unsigned short, l3);
        ((ushort4*)xhi)[idx] = hp;
        ((ushort4*)xlo)[idx] = lp;
    }
}

// ---------------------------------------------------------------------------
// Kernel B: transpose + convert w1 [DIMK][HIDN] fp32 -> w1t hi/lo [HIDN][DIMK]
// ---------------------------------------------------------------------------
__global__ __launch_bounds__(256) void conv_w1_kernel(
    const float* w1, f16* wthi, f16* wtlo)
{
    __shared__ float t[64][65];
    const int bx = blockIdx.x & 15;        // n-tile (HIDN/64 = 16)
    const int by = blockIdx.x >> 4;        // k-tile (DIMK/64 = 64)
    #pragma unroll
    for (int i = 0; i < 16; ++i) {
        const int e = threadIdx.x + i * 256;
        const int r = e >> 6, c = e & 63;
        t[r][c] = w1[(size_t)(by * 64 + r) * HIDN + bx * 64 + c];
    }
    __syncthreads();
    #pragma unroll
    for (int i = 0; i < 16; ++i) {
        const int e = threadIdx.x + i * 256;
        const int nrow = e >> 6, kcol = e & 63;
        f16 h, l;
        split_f16(t[kcol][nrow], h, l);
        const size_t o = (size_t)(bx * 64 + nrow) * DIMK + by * 64 + kcol;
        wthi[o] = h;
        wtlo[o] = l;
    }
}

// ---------------------------------------------------------------------------
// Kernel C: FUSED 3-term f16 MFMA GEMM + relu/w2 epilogue -> score partials.
// Per K-step all 4 tiles staged (xhi, xlo_s, whi, wlo_s) and 48 MFMA issued
// between one barrier pair:
//   acc += (xhi*2^11)*whi + xhi*wlo_s + xlo_s*whi      (all at 2^11 scale)
// The 2^11 on the hi*hi term is applied to the xhi FRAGMENT in registers via
// packed-f16 multiply (exact pow2; |xhi|*2048 < 65504 for N(0,1) data).
// 128x128 tile, BK=32, 4 waves (2x2), 16x16x32 MFMA, 4x4 frags/wave.
// partials[slot][token], slot = nblk*2 + wc (16 slots), summed by router.
// ---------------------------------------------------------------------------
#define GBM 128
#define GBN 128
#define GBK 32

__global__ __launch_bounds__(256) void mod_mfma_kernel(
    const f16* xhi, const f16* xlo, const f16* wthi, const f16* wtlo,
    const float* b1, const float* w2, float* partials)
{
    // 4 tiles x 8KB = 32 KB, single-buffered
    __shared__ __align__(16) f16 tiles[4 * GBM * GBK];

    const int tid  = threadIdx.x;
    const int lane = tid & 63;
    const int wid  = tid >> 6;
    const int wr   = wid >> 1;
    const int wc   = wid & 1;

    // XCD-chunked bijective swizzle (1024 blocks % 8 == 0)
    const int bid  = blockIdx.x;
    const int v    = (bid & 7) * 128 + (bid >> 3);
    const int nblk = v & 7;
    const int mblk = v >> 3;
    const int tokBase = mblk * GBM;
    const int nBase   = nblk * GBN;

    // staging constants: wave wid fills chunks wid*2+{0,1} (1KB each) per tile
    int row[2], sof[2];
    #pragma unroll
    for (int i = 0; i < 2; ++i) {
        const int r = (wid * 2 + i) * 16 + (lane >> 2);
        row[i] = r;
        sof[i] = ((lane & 3) << 4) ^ swzf(r);   // pre-swizzled source slot
    }

    // fragment-read byte offsets (tile-local, constant per thread)
    int aoff[4], boff[4];
    #pragma unroll
    for (int m = 0; m < 4; ++m) {
        const int r = wr * 64 + m * 16 + (lane & 15);
        aoff[m] = r * 64 + (((lane >> 4) << 4) ^ swzf(r));
        const int c = wc * 64 + m * 16 + (lane & 15);
        boff[m] = c * 64 + (((lane >> 4) << 4) ^ swzf(c));
    }

    f32x4 acc[4][4];
    #pragma unroll
    for (int m = 0; m < 4; ++m)
        #pragma unroll
        for (int n = 0; n < 4; ++n)
            #pragma unroll
            for (int j = 0; j < 4; ++j) acc[m][n][j] = 0.0f;

    const f16 kS = (f16)2048.0f;

    for (int k0 = 0; k0 < DIMK; k0 += GBK) {
        // stage tile t: 0=xhi, 1=xlo_s (A side), 2=whi, 3=wlo_s (B side)
        #pragma unroll
        for (int t = 0; t < 4; ++t) {
            const f16* g = (t == 0) ? xhi : (t == 1) ? xlo : (t == 2) ? wthi : wtlo;
            const int rbase = (t < 2) ? tokBase : nBase;
            #pragma unroll
            for (int i = 0; i < 2; ++i) {
                load_lds16((const char*)g + ((size_t)(rbase + row[i]) * DIMK + k0) * 2 + sof[i],
                           (char*)tiles + t * 8192 + (wid * 2 + i) * 1024);
            }
        }
        __syncthreads();   // drains vmcnt (global_load_lds)

        f16x8 af_h[4], af_s[4], bf_h[4];
        #pragma unroll
        for (int n = 0; n < 4; ++n)
            bf_h[n] = *(const f16x8*)((const char*)tiles + 2 * 8192 + boff[n]);
        #pragma unroll
        for (int m = 0; m < 4; ++m) {
            af_h[m] = *(const f16x8*)((const char*)tiles + 0 * 8192 + aoff[m]);
            af_s[m] = af_h[m] * kS;       // exact pow2 scale, packed f16
        }
        // term 1: (xhi*2^11) * whi
        #pragma unroll
        for (int m = 0; m < 4; ++m)
            #pragma unroll
            for (int n = 0; n < 4; ++n)
                acc[m][n] = __builtin_amdgcn_mfma_f32_16x16x32_f16(
                    af_s[m], bf_h[n], acc[m][n], 0, 0, 0);

        // term 2: xhi * wlo_s
        f16x8 bf_l[4];
        #pragma unroll
        for (int n = 0; n < 4; ++n)
            bf_l[n] = *(const f16x8*)((const char*)tiles + 3 * 8192 + boff[n]);
        #pragma unroll
        for (int m = 0; m < 4; ++m)
            #pragma unroll
            for (int n = 0; n < 4; ++n)
                acc[m][n] = __builtin_amdgcn_mfma_f32_16x16x32_f16(
                    af_h[m], bf_l[n], acc[m][n], 0, 0, 0);

        // term 3: xlo_s * whi
        f16x8 af_l[4];
        #pragma unroll
        for (int m = 0; m < 4; ++m)
            af_l[m] = *(const f16x8*)((const char*)tiles + 1 * 8192 + aoff[m]);
        #pragma unroll
        for (int m = 0; m < 4; ++m)
            #pragma unroll
            for (int n = 0; n < 4; ++n)
                acc[m][n] = __builtin_amdgcn_mfma_f32_16x16x32_f16(
                    af_l[m], bf_h[n], acc[m][n], 0, 0, 0);

        __syncthreads();   // reads done before next tile overwrites LDS
    }

    // epilogue: h = acc/2048 + b1; partial = sum relu(h)*w2 over wave's cols.
    // C/D layout: col = lane&15, row = (lane>>4)*4 + j per 16x16 fragment.
    float rp[4][4];
    #pragma unroll
    for (int m = 0; m < 4; ++m)
        #pragma unroll
        for (int j = 0; j < 4; ++j) rp[m][j] = 0.0f;

    #pragma unroll
    for (int n = 0; n < 4; ++n) {
        const int col = nBase + wc * 64 + n * 16 + (lane & 15);
        const float wv = w2[col];
        const float bb = b1[col];
        #pragma unroll
        for (int m = 0; m < 4; ++m)
            #pragma unroll
            for (int j = 0; j < 4; ++j) {
                float h = fmaf(acc[m][n][j], INV_LO_SCALE, bb);
                h = fmaxf(h, 0.0f);
                rp[m][j] = fmaf(h, wv, rp[m][j]);
            }
    }
    #pragma unroll
    for (int off = 1; off < 16; off <<= 1)
        #pragma unroll
        for (int m = 0; m < 4; ++m)
            #pragma unroll
            for (int j = 0; j < 4; ++j)
                rp[m][j] += __shfl_xor(rp[m][j], off, 64);

    if ((lane & 15) == 0) {
        const int q = lane >> 4;
        const int slot = nblk * 2 + wc;
        float* pdst = partials + (size_t)slot * NTOK + tokBase + wr * 64 + q * 4;
        #pragma unroll
        for (int m = 0; m < 4; ++m)
            #pragma unroll
            for (int j = 0; j < 4; ++j)
                pdst[m * 16 + j] = rp[m][j];
    }
}

// ---------------------------------------------------------------------------
// Kernel D: router (validated semantics), scores = sum of 16 partials + b2.
// ---------------------------------------------------------------------------
__global__ __launch_bounds__(1024) void mod_route_part_kernel(
    const float* partials, const float* b2,
    float* mask_out, float* rw_out)
{
    __shared__ float s[SLEN];
    __shared__ int   sg[2][1024];
    __shared__ int   se[2][1024];
    __shared__ float red[1024];

    const int b   = blockIdx.x;
    const int tid = threadIdx.x;
    const int base = tid * 4;
    const float bias2 = b2[0];

    float og[4];
    #pragma unroll
    for (int u = 0; u < 4; ++u) {
        const size_t tok = (size_t)b * SLEN + base + u;
        float sum = bias2;
        #pragma unroll
        for (int p = 0; p < NPART; ++p) sum += partials[(size_t)p * NTOK + tok];
        og[u] = sum;
        s[base + u] = sum;
    }
    __syncthreads();

    for (int k = 2; k <= SLEN; k <<= 1) {
        for (int j = k >> 1; j > 0; j >>= 1) {
            for (int i = tid; i < SLEN; i += 1024) {
                const int ixj = i ^ j;
                if (ixj > i) {
                    const float a = s[i];
                    const float c = s[ixj];
                    const bool descRegion = ((i & k) == 0);
                    if (descRegion ? (a < c) : (a > c)) { s[i] = c; s[ixj] = a; }
                }
            }
            __syncthreads();
        }
    }

    const float maxv      = s[0];
    const float threshold = s[KSEL - 1];

    float part = 0.f;
    for (int i = tid; i < KSEL; i += 1024) part += expf(s[i] - maxv);
    red[tid] = part;
    __syncthreads();
    for (int off = 512; off > 0; off >>= 1) {
        if (tid < off) red[tid] += red[tid + off];
        __syncthreads();
    }
    const float sumexp = red[0];
    __syncthreads();

    int gcnt = 0, ecnt = 0;
    #pragma unroll
    for (int u = 0; u < 4; ++u) {
        gcnt += (og[u] > threshold);
        ecnt += (og[u] == threshold);
    }

    int cur = 0;
    sg[0][tid] = gcnt;
    se[0][tid] = ecnt;
    __syncthreads();
    for (int off = 1; off < 1024; off <<= 1) {
        const int nxt = cur ^ 1;
        int vg = sg[cur][tid];
        int ve = se[cur][tid];
        if (tid >= off) { vg += sg[cur][tid - off]; ve += se[cur][tid - off]; }
        sg[nxt][tid] = vg;
        se[nxt][tid] = ve;
        __syncthreads();
        cur = nxt;
    }
    const int total_gt = sg[cur][1023];
    const int R = KSEL - total_gt;
    int pgi = sg[cur][tid] - gcnt;
    int pei = se[cur][tid] - ecnt;

    const float inv_sum = 1.0f / sumexp;
    #pragma unroll
    for (int u = 0; u < 4; ++u) {
        const bool isg = og[u] > threshold;
        const bool ise = og[u] == threshold;
        const bool sel = isg || (ise && pei < R);
        float rwv = 0.f;
        if (sel) {
            const int rank = pgi + (pei < R ? pei : R);
            rwv = expf(s[rank] - maxv) * inv_sum;
        }
        const size_t oi = (size_t)b * SLEN + base + u;
        mask_out[oi] = sel ? 1.0f : 0.0f;
        rw_out[oi]   = rwv;
        pgi += isg;
        pei += ise;
    }
}

// ---------------------------------------------------------------------------
// Fallback path (ws too small): validated fp32 VALU scorer
// ---------------------------------------------------------------------------
#define BM 64
#define BN 256
#define BK 32
#define THREADS 512

__global__ __launch_bounds__(THREADS) void mod_score_kernel(
    const float* x, const float* w1, const float* b1,
    const float* w2, const float* b2, float* scores)
{
    __shared__ float Xs[BK][BM + 4];
    __shared__ float Ws[BK][BN];

    const int tid = threadIdx.x;
    const int tx = tid & 31;
    const int ty = tid >> 5;
    const int tokBase = blockIdx.x * BM;

    float sp[4] = {0.f, 0.f, 0.f, 0.f};
    const float bias2 = b2[0];

    for (int hc = 0; hc < HIDN; hc += BN) {
        float acc[4][8];
        #pragma unroll
        for (int m = 0; m < 4; ++m)
            #pragma unroll
            for (int n = 0; n < 8; ++n) acc[m][n] = 0.f;

        for (int k0 = 0; k0 < DIMK; k0 += BK) {
            {
                const int r  = tid >> 3;
                const int c4 = tid & 7;
                const float4 vv = *(const float4*)(x + (size_t)(tokBase + r) * DIMK + k0 + c4 * 4);
                Xs[c4 * 4 + 0][r] = vv.x;
                Xs[c4 * 4 + 1][r] = vv.y;
                Xs[c4 * 4 + 2][r] = vv.z;
                Xs[c4 * 4 + 3][r] = vv.w;
            }
            #pragma unroll
            for (int i = 0; i < 4; ++i) {
                const int idx = tid + i * THREADS;
                const int r   = idx >> 6;
                const int c4  = idx & 63;
                const float4 vv = *(const float4*)(w1 + (size_t)(k0 + r) * HIDN + hc + c4 * 4);
                *(float4*)&Ws[r][c4 * 4] = vv;
            }
            __syncthreads();

            #pragma unroll 8
            for (int k = 0; k < BK; ++k) {
                const float4 xv = *(const float4*)&Xs[k][ty * 4];
                const float4 wa = *(const float4*)&Ws[k][tx * 4];
                const float4 wb = *(const float4*)&Ws[k][128 + tx * 4];
                const float xm[4] = {xv.x, xv.y, xv.z, xv.w};
                const float wn[8] = {wa.x, wa.y, wa.z, wa.w, wb.x, wb.y, wb.z, wb.w};
                #pragma unroll
                for (int m = 0; m < 4; ++m)
                    #pragma unroll
                    for (int n = 0; n < 8; ++n)
                        acc[m][n] = fmaf(xm[m], wn[n], acc[m][n]);
            }
            __syncthreads();
        }

        #pragma unroll
        for (int half = 0; half < 2; ++half) {
            #pragma unroll
            for (int n = 0; n < 4; ++n) {
                const int h = hc + half * 128 + tx * 4 + n;
                const float wv = w2[h];
                const float bb = b1[h];
                #pragma unroll
                for (int m = 0; m < 4; ++m) {
                    float hv = acc[m][half * 4 + n] + bb;
                    hv = fmaxf(hv, 0.f);
                    sp[m] = fmaf(hv, wv, sp[m]);
                }
            }
        }
    }

    #pragma unroll
    for (int off = 1; off < 32; off <<= 1) {
        #pragma unroll
        for (int m = 0; m < 4; ++m) sp[m] += __shfl_xor(sp[m], off, 64);
    }
    if (tx == 0) {
        #pragma unroll
        for (int m = 0; m < 4; ++m)
            scores[tokBase + ty * 4 + m] = sp[m] + bias2;
    }
}

__global__ __launch_bounds__(1024) void mod_route_kernel(
    const float* scores, float* mask_out, float* rw_out)
{
    __shared__ float s[SLEN];
    __shared__ int   sg[2][1024];
    __shared__ int   se[2][1024];
    __shared__ float red[1024];

    const int b   = blockIdx.x;
    const int tid = threadIdx.x;
    const float* rowp = scores + (size_t)b * SLEN;
    const int base = tid * 4;

    const float4 ov = *(const float4*)(rowp + base);
    float og[4] = {ov.x, ov.y, ov.z, ov.w};
    s[base + 0] = ov.x;
    s[base + 1] = ov.y;
    s[base + 2] = ov.z;
    s[base + 3] = ov.w;
    __syncthreads();

    for (int k = 2; k <= SLEN; k <<= 1) {
        for (int j = k >> 1; j > 0; j >>= 1) {
            for (int i = tid; i < SLEN; i += 1024) {
                const int ixj = i ^ j;
                if (ixj > i) {
                    const float a = s[i];
                    const float c = s[ixj];
                    const bool descRegion = ((i & k) == 0);
                    if (descRegion ? (a < c) : (a > c)) { s[i] = c; s[ixj] = a; }
                }
            }
            __syncthreads();
        }
    }

    const float maxv      = s[0];
    const float threshold = s[KSEL - 1];

    float part = 0.f;
    for (int i = tid; i < KSEL; i += 1024) part += expf(s[i] - maxv);
    red[tid] = part;
    __syncthreads();
    for (int off = 512; off > 0; off >>= 1) {
        if (tid < off) red[tid] += red[tid + off];
        __syncthreads();
    }
    const float sumexp = red[0];
    __syncthreads();

    int gcnt = 0, ecnt = 0;
    #pragma unroll
    for (int u = 0; u < 4; ++u) {
        gcnt += (og[u] > threshold);
        ecnt += (og[u] == threshold);
    }

    int cur = 0;
    sg[0][tid] = gcnt;
    se[0][tid] = ecnt;
    __syncthreads();
    for (int off = 1; off < 1024; off <<= 1) {
        const int nxt = cur ^ 1;
        int vg = sg[cur][tid];
        int ve = se[cur][tid];
        if (tid >= off) { vg += sg[cur][tid - off]; ve += se[cur][tid - off]; }
        sg[nxt][tid] = vg;
        se[nxt][tid] = ve;
        __syncthreads();
        cur = nxt;
    }
    const int total_gt = sg[cur][1023];
    const int R = KSEL - total_gt;
    int pgi = sg[cur][tid] - gcnt;
    int pei = se[cur][tid] - ecnt;

    const float inv_sum = 1.0f / sumexp;
    #pragma unroll
    for (int u = 0; u < 4; ++u) {
        const bool isg = og[u] > threshold;
        const bool ise = og[u] == threshold;
        const bool sel = isg || (ise && pei < R);
        float rwv = 0.f;
        if (sel) {
            const int rank = pgi + (pei < R ? pei : R);
            rwv = expf(s[rank] - maxv) * inv_sum;
        }
        const size_t oi = (size_t)b * SLEN + base + u;
        mask_out[oi] = sel ? 1.0f : 0.0f;
        rw_out[oi]   = rwv;
        pgi += isg;
        pei += ise;
    }
}

// ---------------------------------------------------------------------------
extern "C" void kernel_launch(void* const* d_in, const int* in_sizes, int n_in,
                              void* d_out, int out_size, void* d_ws, size_t ws_size,
                              hipStream_t stream) {
    const float* x  = (const float*)d_in[0];
    const float* w1 = (const float*)d_in[1];
    const float* b1 = (const float*)d_in[2];
    const float* w2 = (const float*)d_in[3];
    const float* b2 = (const float*)d_in[4];

    float* out      = (float*)d_out;
    float* mask_out = out;            // [4, 4096]
    float* rw_out   = out + NTOK;     // [4, 4096]

    const size_t partials_b = (size_t)NPART * NTOK * 4;          // 1 MB
    const size_t xsplit_b   = (size_t)NTOK * DIMK * 2;           // 134 MB each
    const size_t wsplit_b   = (size_t)HIDN * DIMK * 2;           // 8 MB each
    const size_t needed     = partials_b + 2 * xsplit_b + 2 * wsplit_b;

    if (ws_size >= needed) {
        char* wsb = (char*)d_ws;
        float* partials = (float*)wsb;
        f16* xhi  = (f16*)(wsb + partials_b);
        f16* xlo  = xhi + (size_t)NTOK * DIMK;
        f16* wthi = (f16*)(wsb + partials_b + 2 * xsplit_b);
        f16* wtlo = wthi + (size_t)HIDN * DIMK;

        conv_x_kernel<<<2048, 256, 0, stream>>>(x, xhi, xlo);
        conv_w1_kernel<<<1024, 256, 0, stream>>>(w1, wthi, wtlo);
        mod_mfma_kernel<<<1024, 256, 0, stream>>>(xhi, xlo, wthi, wtlo, b1, w2, partials);
        mod_route_part_kernel<<<NBATCH, 1024, 0, stream>>>(partials, b2, mask_out, rw_out);
    } else {
        float* scores = (ws_size >= (size_t)NTOK * sizeof(float)) ? (float*)d_ws : rw_out;
        mod_score_kernel<<<NTOK / BM, THREADS, 0, stream>>>(x, w1, b1, w2, b2, scores);
        mod_route_kernel<<<NBATCH, 1024, 0, stream>>>(scores, mask_out, rw_out);
    }
}

// Round 6
// 414.877 us; speedup vs baseline: 1.8976x; 1.4701x over previous
//
#include <hip/hip_runtime.h>
#include <math.h>

typedef _Float16 f16;
typedef _Float16 f16x8 __attribute__((ext_vector_type(8)));
typedef float    f32x4 __attribute__((ext_vector_type(4)));

#define DIMK 4096
#define HIDN 1024
#define NTOK 16384
#define SLEN 4096
#define NBATCH 4
#define KSEL 2048
#define NPART 16

#define F16_MIN_NORMAL 6.1035156e-5f
#define LO_SCALE 2048.0f
#define INV_LO_SCALE (1.0f/2048.0f)

// ---------------------------------------------------------------------------
// helpers
// ---------------------------------------------------------------------------
__device__ __forceinline__ void load_lds16(const void* g, void* l) {
    __builtin_amdgcn_global_load_lds(
        (const __attribute__((address_space(1))) unsigned int*)g,
        (__attribute__((address_space(3))) unsigned int*)l, 16, 0, 0);
}
// XOR swizzle of the 16B slot index within a 64B LDS row (2-way-max banks).
__device__ __forceinline__ int swzf(int row) { return ((row >> 1) & 3) << 4; }

// split v = hi + lo*2^-11, hi/lo f16, hi clamped out of subnormal range
// (flush-robust), lo pre-scaled by 2^11 into normal range.
__device__ __forceinline__ void split_f16(float v, f16& hi, f16& lo) {
    f16 h = (f16)v;
    float hf = (float)h;
    if (fabsf(hf) < F16_MIN_NORMAL) { h = (f16)0.0f; hf = 0.0f; }
    hi = h;
    lo = (f16)((v - hf) * LO_SCALE);
}

__device__ __forceinline__ f32x4 mfma16(f16x8 a, f16x8 b, f32x4 c) {
    return __builtin_amdgcn_mfma_f32_16x16x32_f16(a, b, c, 0, 0, 0);
}

// ---------------------------------------------------------------------------
// Kernel B: transpose + convert w1 [DIMK][HIDN] fp32 -> w1t hi/lo [HIDN][DIMK]
// ---------------------------------------------------------------------------
__global__ __launch_bounds__(256) void conv_w1_kernel(
    const float* w1, f16* wthi, f16* wtlo)
{
    __shared__ float t[64][65];
    const int bx = blockIdx.x & 15;        // n-tile (HIDN/64 = 16)
    const int by = blockIdx.x >> 4;        // k-tile (DIMK/64 = 64)
    #pragma unroll
    for (int i = 0; i < 16; ++i) {
        const int e = threadIdx.x + i * 256;
        const int r = e >> 6, c = e & 63;
        t[r][c] = w1[(size_t)(by * 64 + r) * HIDN + bx * 64 + c];
    }
    __syncthreads();
    #pragma unroll
    for (int i = 0; i < 16; ++i) {
        const int e = threadIdx.x + i * 256;
        const int nrow = e >> 6, kcol = e & 63;
        f16 h, l;
        split_f16(t[kcol][nrow], h, l);
        const size_t o = (size_t)(bx * 64 + nrow) * DIMK + by * 64 + kcol;
        wthi[o] = h;
        wtlo[o] = l;
    }
}

// ---------------------------------------------------------------------------
// Kernel C: 256x256-tile fused 3-term f16-split MFMA scorer.
//   acc += (xhi*2^11)*whi + xhi*wlo_s + xlo_s*whi    (all at 2^11 scale)
// A-side: x read fp32 DIRECTLY, split in registers, ds_write_b128 swizzled
//         (no conv_x kernel; bytes/elem identical to hi+lo pair).
// B-side: wthi/wtlo via global_load_lds, pre-swizzled source.
// BK=32, 8 waves (2Mx4N), per-wave 128x64 out, acc[8][4] f32x4 = 128 VGPR.
// Double-buffered 2x64KB LDS; ONE barrier per K-tile; loads for t+1 issued
// at top of tile t (full-tile lead hides HBM latency); 4 C-quadrant phases
// with setprio(1) around each 24-MFMA cluster.
// partials[slot][token], slot = nblk*4 + wc (16 slots), summed by router.
// ---------------------------------------------------------------------------
#define TBM 256
#define TBN 256
#define TBK 32
#define BUF_BYTES 65536   // Ahi@0(16K) Alo@16K Bhi@32K Blo@48K

__global__ __launch_bounds__(512, 2) void mod_mfma256_kernel(
    const float* x, const f16* wthi, const f16* wtlo,
    const float* b1, const float* w2, float* partials)
{
    __shared__ __align__(16) char lds[2 * BUF_BYTES];   // 128 KB

    const int tid  = threadIdx.x;
    const int lane = tid & 63;
    const int wid  = tid >> 6;
    const int wr   = wid >> 2;       // 0..1
    const int wc   = wid & 3;        // 0..3

    // XCD-chunked bijective swizzle: 256 blocks % 8 == 0
    const int bid  = blockIdx.x;
    const int v    = (bid & 7) * 32 + (bid >> 3);
    const int nblk = v & 3;          // 0..3
    const int mblk = v >> 2;         // 0..63
    const int tokBase = mblk * TBM;
    const int nBase   = nblk * TBN;

    // ---- A staging constants: pair p = tid + i*512: row=p>>2, kqq=p&3
    int arow[2], akqq[2], adst[2];
    #pragma unroll
    for (int i = 0; i < 2; ++i) {
        const int p = tid + i * 512;
        arow[i] = p >> 2;
        akqq[i] = p & 3;
        adst[i] = arow[i] * 64 + ((akqq[i] ^ ((arow[i] >> 1) & 3)) << 4);
    }
    // ---- B staging constants: 32 chunks of 1KB (16 rows x 64B)
    const f16* bsrcm[4];
    int bsrcoff[4], bdst[4];
    #pragma unroll
    for (int j = 0; j < 4; ++j) {
        const int c    = wid * 4 + j;            // 0..31
        const int half = c >> 4;                 // 0=hi 1=lo
        const int rloc = (c & 15) * 16 + (lane >> 2);
        bsrcm[j]   = half ? wtlo : wthi;
        bsrcoff[j] = (nBase + rloc) * (DIMK * 2) + (((lane & 3) << 4) ^ swzf(rloc));
        bdst[j]    = 32768 + half * 16384 + (c & 15) * 1024;
    }

    // ---- fragment read byte offsets (hi regions; lo = +16384)
    int aoff[8], boff[4];
    #pragma unroll
    for (int m = 0; m < 8; ++m) {
        const int r = wr * 128 + m * 16 + (lane & 15);
        aoff[m] = r * 64 + (((lane >> 4) ^ ((r >> 1) & 3)) << 4);
    }
    #pragma unroll
    for (int n = 0; n < 4; ++n) {
        const int c = wc * 64 + n * 16 + (lane & 15);
        boff[n] = 32768 + c * 64 + (((lane >> 4) ^ ((c >> 1) & 3)) << 4);
    }

    f32x4 acc[8][4];
    #pragma unroll
    for (int m = 0; m < 8; ++m)
        #pragma unroll
        for (int n = 0; n < 4; ++n)
            #pragma unroll
            for (int j = 0; j < 4; ++j) acc[m][n][j] = 0.0f;

    const f16 kS = (f16)LO_SCALE;

    // ---- prologue: stage tile 0 into buffer 0
    {
        float4 a0[2], a1[2];
        #pragma unroll
        for (int i = 0; i < 2; ++i) {
            const float* src = x + (size_t)(tokBase + arow[i]) * DIMK + akqq[i] * 8;
            a0[i] = *(const float4*)(src);
            a1[i] = *(const float4*)(src + 4);
        }
        #pragma unroll
        for (int j = 0; j < 4; ++j)
            load_lds16((const char*)bsrcm[j] + bsrcoff[j], lds + bdst[j]);
        #pragma unroll
        for (int i = 0; i < 2; ++i) {
            f16x8 h8, l8;
            const float vv[8] = {a0[i].x, a0[i].y, a0[i].z, a0[i].w,
                                 a1[i].x, a1[i].y, a1[i].z, a1[i].w};
            #pragma unroll
            for (int e = 0; e < 8; ++e) { f16 h, l; split_f16(vv[e], h, l); h8[e] = h; l8[e] = l; }
            *(f16x8*)(lds + adst[i]) = h8;
            *(f16x8*)(lds + 16384 + adst[i]) = l8;
        }
        __syncthreads();
    }

    for (int t = 0; t < DIMK / TBK; ++t) {
        const int cur = (t & 1) * BUF_BYTES;
        const int nxt = BUF_BYTES - cur;
        const bool pf = (t + 1 < DIMK / TBK);
        const int k0n = (t + 1) * TBK;

        // [1] issue A fp32 loads for t+1 (to regs)
        float4 a0[2], a1[2];
        if (pf) {
            #pragma unroll
            for (int i = 0; i < 2; ++i) {
                const float* src = x + (size_t)(tokBase + arow[i]) * DIMK + k0n + akqq[i] * 8;
                a0[i] = *(const float4*)(src);
                a1[i] = *(const float4*)(src + 4);
            }
            // [2] issue B global_load_lds for t+1 into nxt
            #pragma unroll
            for (int j = 0; j < 4; ++j)
                load_lds16((const char*)bsrcm[j] + bsrcoff[j] + k0n * 2, lds + nxt + bdst[j]);
        }

        f16x8 afh[4], afl[4], bh0[2], bl0[2], bh1[2], bl1[2];
        // ---- phase (0,0): m 0..3 x n 0..1
        #pragma unroll
        for (int m = 0; m < 4; ++m) {
            afh[m] = *(const f16x8*)(lds + cur + aoff[m]);
            afl[m] = *(const f16x8*)(lds + cur + 16384 + aoff[m]);
        }
        #pragma unroll
        for (int n = 0; n < 2; ++n) {
            bh0[n] = *(const f16x8*)(lds + cur + boff[n]);
            bl0[n] = *(const f16x8*)(lds + cur + 16384 + boff[n]);
        }
        __builtin_amdgcn_s_setprio(1);
        #pragma unroll
        for (int m = 0; m < 4; ++m) {
            const f16x8 afs = afh[m] * kS;
            #pragma unroll
            for (int n = 0; n < 2; ++n) {
                acc[m][n] = mfma16(afs,    bh0[n], acc[m][n]);
                acc[m][n] = mfma16(afh[m], bl0[n], acc[m][n]);
                acc[m][n] = mfma16(afl[m], bh0[n], acc[m][n]);
            }
        }
        __builtin_amdgcn_s_setprio(0);
        // ---- phase (0,1): m 0..3 x n 2..3
        #pragma unroll
        for (int n = 0; n < 2; ++n) {
            bh1[n] = *(const f16x8*)(lds + cur + boff[2 + n]);
            bl1[n] = *(const f16x8*)(lds + cur + 16384 + boff[2 + n]);
        }
        __builtin_amdgcn_s_setprio(1);
        #pragma unroll
        for (int m = 0; m < 4; ++m) {
            const f16x8 afs = afh[m] * kS;
            #pragma unroll
            for (int n = 0; n < 2; ++n) {
                acc[m][2 + n] = mfma16(afs,    bh1[n], acc[m][2 + n]);
                acc[m][2 + n] = mfma16(afh[m], bl1[n], acc[m][2 + n]);
                acc[m][2 + n] = mfma16(afl[m], bh1[n], acc[m][2 + n]);
            }
        }
        __builtin_amdgcn_s_setprio(0);
        // [5] convert + ds_write A for t+1 (compiler inserts the vmcnt wait)
        if (pf) {
            #pragma unroll
            for (int i = 0; i < 2; ++i) {
                f16x8 h8, l8;
                const float vv[8] = {a0[i].x, a0[i].y, a0[i].z, a0[i].w,
                                     a1[i].x, a1[i].y, a1[i].z, a1[i].w};
                #pragma unroll
                for (int e = 0; e < 8; ++e) { f16 h, l; split_f16(vv[e], h, l); h8[e] = h; l8[e] = l; }
                *(f16x8*)(lds + nxt + adst[i]) = h8;
                *(f16x8*)(lds + nxt + 16384 + adst[i]) = l8;
            }
        }
        // ---- phase (1,0): m 4..7 x n 0..1
        #pragma unroll
        for (int m = 0; m < 4; ++m) {
            afh[m] = *(const f16x8*)(lds + cur + aoff[4 + m]);
            afl[m] = *(const f16x8*)(lds + cur + 16384 + aoff[4 + m]);
        }
        __builtin_amdgcn_s_setprio(1);
        #pragma unroll
        for (int m = 0; m < 4; ++m) {
            const f16x8 afs = afh[m] * kS;
            #pragma unroll
            for (int n = 0; n < 2; ++n) {
                acc[4 + m][n] = mfma16(afs,    bh0[n], acc[4 + m][n]);
                acc[4 + m][n] = mfma16(afh[m], bl0[n], acc[4 + m][n]);
                acc[4 + m][n] = mfma16(afl[m], bh0[n], acc[4 + m][n]);
            }
        }
        __builtin_amdgcn_s_setprio(0);
        // ---- phase (1,1): m 4..7 x n 2..3
        __builtin_amdgcn_s_setprio(1);
        #pragma unroll
        for (int m = 0; m < 4; ++m) {
            const f16x8 afs = afh[m] * kS;
            #pragma unroll
            for (int n = 0; n < 2; ++n) {
                acc[4 + m][2 + n] = mfma16(afs,    bh1[n], acc[4 + m][2 + n]);
                acc[4 + m][2 + n] = mfma16(afh[m], bl1[n], acc[4 + m][2 + n]);
                acc[4 + m][2 + n] = mfma16(afl[m], bh1[n], acc[4 + m][2 + n]);
            }
        }
        __builtin_amdgcn_s_setprio(0);

        __syncthreads();   // one barrier per K-tile: cur reads done, nxt ready
    }

    // ---- epilogue: h = acc/2048 + b1; partial = sum relu(h)*w2 over 64 cols
    // C/D layout (m89): col = lane&15, row = (lane>>4)*4 + j per fragment.
    float rp[8][4];
    #pragma unroll
    for (int m = 0; m < 8; ++m)
        #pragma unroll
        for (int j = 0; j < 4; ++j) rp[m][j] = 0.0f;

    #pragma unroll
    for (int n = 0; n < 4; ++n) {
        const int col = nBase + wc * 64 + n * 16 + (lane & 15);
        const float wv = w2[col];
        const float bb = b1[col];
        #pragma unroll
        for (int m = 0; m < 8; ++m)
            #pragma unroll
            for (int j = 0; j < 4; ++j) {
                float h = fmaf(acc[m][n][j], INV_LO_SCALE, bb);
                h = fmaxf(h, 0.0f);
                rp[m][j] = fmaf(h, wv, rp[m][j]);
            }
    }
    #pragma unroll
    for (int off = 1; off < 16; off <<= 1)
        #pragma unroll
        for (int m = 0; m < 8; ++m)
            #pragma unroll
            for (int j = 0; j < 4; ++j)
                rp[m][j] += __shfl_xor(rp[m][j], off, 64);

    if ((lane & 15) == 0) {
        const int q = lane >> 4;
        const int slot = nblk * 4 + wc;
        float* pdst = partials + (size_t)slot * NTOK + tokBase + wr * 128 + q * 4;
        #pragma unroll
        for (int m = 0; m < 8; ++m)
            #pragma unroll
            for (int j = 0; j < 4; ++j)
                pdst[m * 16 + j] = rp[m][j];
    }
}

// ---------------------------------------------------------------------------
// Kernel D: router (validated semantics), scores = sum of 16 partials + b2.
// ---------------------------------------------------------------------------
__global__ __launch_bounds__(1024) void mod_route_part_kernel(
    const float* partials, const float* b2,
    float* mask_out, float* rw_out)
{
    __shared__ float s[SLEN];
    __shared__ int   sg[2][1024];
    __shared__ int   se[2][1024];
    __shared__ float red[1024];

    const int b   = blockIdx.x;
    const int tid = threadIdx.x;
    const int base = tid * 4;
    const float bias2 = b2[0];

    float og[4];
    #pragma unroll
    for (int u = 0; u < 4; ++u) {
        const size_t tok = (size_t)b * SLEN + base + u;
        float sum = bias2;
        #pragma unroll
        for (int p = 0; p < NPART; ++p) sum += partials[(size_t)p * NTOK + tok];
        og[u] = sum;
        s[base + u] = sum;
    }
    __syncthreads();

    for (int k = 2; k <= SLEN; k <<= 1) {
        for (int j = k >> 1; j > 0; j >>= 1) {
            for (int i = tid; i < SLEN; i += 1024) {
                const int ixj = i ^ j;
                if (ixj > i) {
                    const float a = s[i];
                    const float c = s[ixj];
                    const bool descRegion = ((i & k) == 0);
                    if (descRegion ? (a < c) : (a > c)) { s[i] = c; s[ixj] = a; }
                }
            }
            __syncthreads();
        }
    }

    const float maxv      = s[0];
    const float threshold = s[KSEL - 1];

    float part = 0.f;
    for (int i = tid; i < KSEL; i += 1024) part += expf(s[i] - maxv);
    red[tid] = part;
    __syncthreads();
    for (int off = 512; off > 0; off >>= 1) {
        if (tid < off) red[tid] += red[tid + off];
        __syncthreads();
    }
    const float sumexp = red[0];
    __syncthreads();

    int gcnt = 0, ecnt = 0;
    #pragma unroll
    for (int u = 0; u < 4; ++u) {
        gcnt += (og[u] > threshold);
        ecnt += (og[u] == threshold);
    }

    int cur = 0;
    sg[0][tid] = gcnt;
    se[0][tid] = ecnt;
    __syncthreads();
    for (int off = 1; off < 1024; off <<= 1) {
        const int nxt = cur ^ 1;
        int vg = sg[cur][tid];
        int ve = se[cur][tid];
        if (tid >= off) { vg += sg[cur][tid - off]; ve += se[cur][tid - off]; }
        sg[nxt][tid] = vg;
        se[nxt][tid] = ve;
        __syncthreads();
        cur = nxt;
    }
    const int total_gt = sg[cur][1023];
    const int R = KSEL - total_gt;
    int pgi = sg[cur][tid] - gcnt;
    int pei = se[cur][tid] - ecnt;

    const float inv_sum = 1.0f / sumexp;
    #pragma unroll
    for (int u = 0; u < 4; ++u) {
        const bool isg = og[u] > threshold;
        const bool ise = og[u] == threshold;
        const bool sel = isg || (ise && pei < R);
        float rwv = 0.f;
        if (sel) {
            const int rank = pgi + (pei < R ? pei : R);
            rwv = expf(s[rank] - maxv) * inv_sum;
        }
        const size_t oi = (size_t)b * SLEN + base + u;
        mask_out[oi] = sel ? 1.0f : 0.0f;
        rw_out[oi]   = rwv;
        pgi += isg;
        pei += ise;
    }
}

// ---------------------------------------------------------------------------
// Fallback path (ws too small): validated fp32 VALU scorer + router
// ---------------------------------------------------------------------------
#define BM 64
#define BN 256
#define BK 32
#define THREADS 512

__global__ __launch_bounds__(THREADS) void mod_score_kernel(
    const float* x, const float* w1, const float* b1,
    const float* w2, const float* b2, float* scores)
{
    __shared__ float Xs[BK][BM + 4];
    __shared__ float Ws[BK][BN];

    const int tid = threadIdx.x;
    const int tx = tid & 31;
    const int ty = tid >> 5;
    const int tokBase = blockIdx.x * BM;

    float sp[4] = {0.f, 0.f, 0.f, 0.f};
    const float bias2 = b2[0];

    for (int hc = 0; hc < HIDN; hc += BN) {
        float acc[4][8];
        #pragma unroll
        for (int m = 0; m < 4; ++m)
            #pragma unroll
            for (int n = 0; n < 8; ++n) acc[m][n] = 0.f;

        for (int k0 = 0; k0 < DIMK; k0 += BK) {
            {
                const int r  = tid >> 3;
                const int c4 = tid & 7;
                const float4 vv = *(const float4*)(x + (size_t)(tokBase + r) * DIMK + k0 + c4 * 4);
                Xs[c4 * 4 + 0][r] = vv.x;
                Xs[c4 * 4 + 1][r] = vv.y;
                Xs[c4 * 4 + 2][r] = vv.z;
                Xs[c4 * 4 + 3][r] = vv.w;
            }
            #pragma unroll
            for (int i = 0; i < 4; ++i) {
                const int idx = tid + i * THREADS;
                const int r   = idx >> 6;
                const int c4  = idx & 63;
                const float4 vv = *(const float4*)(w1 + (size_t)(k0 + r) * HIDN + hc + c4 * 4);
                *(float4*)&Ws[r][c4 * 4] = vv;
            }
            __syncthreads();

            #pragma unroll 8
            for (int k = 0; k < BK; ++k) {
                const float4 xv = *(const float4*)&Xs[k][ty * 4];
                const float4 wa = *(const float4*)&Ws[k][tx * 4];
                const float4 wb = *(const float4*)&Ws[k][128 + tx * 4];
                const float xm[4] = {xv.x, xv.y, xv.z, xv.w};
                const float wn[8] = {wa.x, wa.y, wa.z, wa.w, wb.x, wb.y, wb.z, wb.w};
                #pragma unroll
                for (int m = 0; m < 4; ++m)
                    #pragma unroll
                    for (int n = 0; n < 8; ++n)
                        acc[m][n] = fmaf(xm[m], wn[n], acc[m][n]);
            }
            __syncthreads();
        }

        #pragma unroll
        for (int half = 0; half < 2; ++half) {
            #pragma unroll
            for (int n = 0; n < 4; ++n) {
                const int h = hc + half * 128 + tx * 4 + n;
                const float wv = w2[h];
                const float bb = b1[h];
                #pragma unroll
                for (int m = 0; m < 4; ++m) {
                    float hv = acc[m][half * 4 + n] + bb;
                    hv = fmaxf(hv, 0.f);
                    sp[m] = fmaf(hv, wv, sp[m]);
                }
            }
        }
    }

    #pragma unroll
    for (int off = 1; off < 32; off <<= 1) {
        #pragma unroll
        for (int m = 0; m < 4; ++m) sp[m] += __shfl_xor(sp[m], off, 64);
    }
    if (tx == 0) {
        #pragma unroll
        for (int m = 0; m < 4; ++m)
            scores[tokBase + ty * 4 + m] = sp[m] + bias2;
    }
}

__global__ __launch_bounds__(1024) void mod_route_kernel(
    const float* scores, float* mask_out, float* rw_out)
{
    __shared__ float s[SLEN];
    __shared__ int   sg[2][1024];
    __shared__ int   se[2][1024];
    __shared__ float red[1024];

    const int b   = blockIdx.x;
    const int tid = threadIdx.x;
    const float* rowp = scores + (size_t)b * SLEN;
    const int base = tid * 4;

    const float4 ov = *(const float4*)(rowp + base);
    float og[4] = {ov.x, ov.y, ov.z, ov.w};
    s[base + 0] = ov.x;
    s[base + 1] = ov.y;
    s[base + 2] = ov.z;
    s[base + 3] = ov.w;
    __syncthreads();

    for (int k = 2; k <= SLEN; k <<= 1) {
        for (int j = k >> 1; j > 0; j >>= 1) {
            for (int i = tid; i < SLEN; i += 1024) {
                const int ixj = i ^ j;
                if (ixj > i) {
                    const float a = s[i];
                    const float c = s[ixj];
                    const bool descRegion = ((i & k) == 0);
                    if (descRegion ? (a < c) : (a > c)) { s[i] = c; s[ixj] = a; }
                }
            }
            __syncthreads();
        }
    }

    const float maxv      = s[0];
    const float threshold = s[KSEL - 1];

    float part = 0.f;
    for (int i = tid; i < KSEL; i += 1024) part += expf(s[i] - maxv);
    red[tid] = part;
    __syncthreads();
    for (int off = 512; off > 0; off >>= 1) {
        if (tid < off) red[tid] += red[tid + off];
        __syncthreads();
    }
    const float sumexp = red[0];
    __syncthreads();

    int gcnt = 0, ecnt = 0;
    #pragma unroll
    for (int u = 0; u < 4; ++u) {
        gcnt += (og[u] > threshold);
        ecnt += (og[u] == threshold);
    }

    int cur = 0;
    sg[0][tid] = gcnt;
    se[0][tid] = ecnt;
    __syncthreads();
    for (int off = 1; off < 1024; off <<= 1) {
        const int nxt = cur ^ 1;
        int vg = sg[cur][tid];
        int ve = se[cur][tid];
        if (tid >= off) { vg += sg[cur][tid - off]; ve += se[cur][tid - off]; }
        sg[nxt][tid] = vg;
        se[nxt][tid] = ve;
        __syncthreads();
        cur = nxt;
    }
    const int total_gt = sg[cur][1023];
    const int R = KSEL - total_gt;
    int pgi = sg[cur][tid] - gcnt;
    int pei = se[cur][tid] - ecnt;

    const float inv_sum = 1.0f / sumexp;
    #pragma unroll
    for (int u = 0; u < 4; ++u) {
        const bool isg = og[u] > threshold;
        const bool ise = og[u] == threshold;
        const bool sel = isg || (ise && pei < R);
        float rwv = 0.f;
        if (sel) {
            const int rank = pgi + (pei < R ? pei : R);
            rwv = expf(s[rank] - maxv) * inv_sum;
        }
        const size_t oi = (size_t)b * SLEN + base + u;
        mask_out[oi] = sel ? 1.0f : 0.0f;
        rw_out[oi]   = rwv;
        pgi += isg;
        pei += ise;
    }
}

// ---------------------------------------------------------------------------
extern "C" void kernel_launch(void* const* d_in, const int* in_sizes, int n_in,
                              void* d_out, int out_size, void* d_ws, size_t ws_size,
                              hipStream_t stream) {
    const float* x  = (const float*)d_in[0];
    const float* w1 = (const float*)d_in[1];
    const float* b1 = (const float*)d_in[2];
    const float* w2 = (const float*)d_in[3];
    const float* b2 = (const float*)d_in[4];

    float* out      = (float*)d_out;
    float* mask_out = out;            // [4, 4096]
    float* rw_out   = out + NTOK;     // [4, 4096]

    const size_t partials_b = (size_t)NPART * NTOK * 4;          // 1 MB
    const size_t wsplit_b   = (size_t)HIDN * DIMK * 2;           // 8 MB each
    const size_t needed     = partials_b + 2 * wsplit_b;         // 17 MB

    if (ws_size >= needed) {
        char* wsb = (char*)d_ws;
        float* partials = (float*)wsb;
        f16* wthi = (f16*)(wsb + partials_b);
        f16* wtlo = wthi + (size_t)HIDN * DIMK;

        conv_w1_kernel<<<1024, 256, 0, stream>>>(w1, wthi, wtlo);
        mod_mfma256_kernel<<<256, 512, 0, stream>>>(x, wthi, wtlo, b1, w2, partials);
        mod_route_part_kernel<<<NBATCH, 1024, 0, stream>>>(partials, b2, mask_out, rw_out);
    } else {
        float* scores = (ws_size >= (size_t)NTOK * sizeof(float)) ? (float*)d_ws : rw_out;
        mod_score_kernel<<<NTOK / BM, THREADS, 0, stream>>>(x, w1, b1, w2, b2, scores);
        mod_route_kernel<<<NBATCH, 1024, 0, stream>>>(scores, mask_out, rw_out);
    }
}

// Round 8
// 402.022 us; speedup vs baseline: 1.9582x; 1.0320x over previous
//
#include <hip/hip_runtime.h>
#include <math.h>

typedef _Float16 f16;
typedef _Float16 f16x8 __attribute__((ext_vector_type(8)));
typedef float    f32x4 __attribute__((ext_vector_type(4)));

#define DIMK 4096
#define HIDN 1024
#define NTOK 16384
#define SLEN 4096
#define NBATCH 4
#define KSEL 2048
#define NPART 16

#define F16_MIN_NORMAL 6.1035156e-5f
#define LO_SCALE 2048.0f
#define INV_LO_SCALE (1.0f/2048.0f)

// ---------------------------------------------------------------------------
// helpers
// ---------------------------------------------------------------------------
__device__ __forceinline__ void load_lds16(const void* g, void* l) {
    __builtin_amdgcn_global_load_lds(
        (const __attribute__((address_space(1))) unsigned int*)g,
        (__attribute__((address_space(3))) unsigned int*)l, 16, 0, 0);
}
// XOR swizzle of the 16B slot index within a 64B LDS row (2-way-max banks).
__device__ __forceinline__ int swzf(int row) { return ((row >> 1) & 3) << 4; }

// Clamped split (w1 conversion only — the clamp is load-bearing there:
// ~0.3% of w1 is f16-subnormal; clamping moves the value into wlo_s).
__device__ __forceinline__ void split_f16(float v, f16& hi, f16& lo) {
    f16 h = (f16)v;
    float hf = (float)h;
    if (fabsf(hf) < F16_MIN_NORMAL) { h = (f16)0.0f; hf = 0.0f; }
    hi = h;
    lo = (f16)((v - hf) * LO_SCALE);
}

// Fast packed split for x (hot path): hi = RTZ(v) via v_cvt_pkrtz (rounding
// mode irrelevant: lo absorbs v-hi exactly; residue <= 2^-22|v|). No
// subnormal clamp: P(|x| < f16_min_normal) ~ 5e-5; even if the MFMA flushes
// those hi inputs the score error is ~1e-6 << 4e-4 rank gap.
// NOTE: __builtin_amdgcn_cvt_pkrtz returns an __fp16 vector; move elements
// with scalar casts (binary16 == binary16, folds to a register copy).
__device__ __forceinline__ void split8(const float4 v0, const float4 v1,
                                       f16x8& h8, f16x8& l8) {
    const auto h01 = __builtin_amdgcn_cvt_pkrtz(v0.x, v0.y);
    const auto h23 = __builtin_amdgcn_cvt_pkrtz(v0.z, v0.w);
    const auto h45 = __builtin_amdgcn_cvt_pkrtz(v1.x, v1.y);
    const auto h67 = __builtin_amdgcn_cvt_pkrtz(v1.z, v1.w);
    const auto l01 = __builtin_amdgcn_cvt_pkrtz((v0.x - (float)h01[0]) * LO_SCALE,
                                                (v0.y - (float)h01[1]) * LO_SCALE);
    const auto l23 = __builtin_amdgcn_cvt_pkrtz((v0.z - (float)h23[0]) * LO_SCALE,
                                                (v0.w - (float)h23[1]) * LO_SCALE);
    const auto l45 = __builtin_amdgcn_cvt_pkrtz((v1.x - (float)h45[0]) * LO_SCALE,
                                                (v1.y - (float)h45[1]) * LO_SCALE);
    const auto l67 = __builtin_amdgcn_cvt_pkrtz((v1.z - (float)h67[0]) * LO_SCALE,
                                                (v1.w - (float)h67[1]) * LO_SCALE);
    h8 = f16x8{(f16)h01[0], (f16)h01[1], (f16)h23[0], (f16)h23[1],
               (f16)h45[0], (f16)h45[1], (f16)h67[0], (f16)h67[1]};
    l8 = f16x8{(f16)l01[0], (f16)l01[1], (f16)l23[0], (f16)l23[1],
               (f16)l45[0], (f16)l45[1], (f16)l67[0], (f16)l67[1]};
}

__device__ __forceinline__ f32x4 mfma16(f16x8 a, f16x8 b, f32x4 c) {
    return __builtin_amdgcn_mfma_f32_16x16x32_f16(a, b, c, 0, 0, 0);
}

// ---------------------------------------------------------------------------
// Kernel B: transpose + convert w1 [DIMK][HIDN] fp32 -> w1t hi/lo [HIDN][DIMK]
// ---------------------------------------------------------------------------
__global__ __launch_bounds__(256) void conv_w1_kernel(
    const float* w1, f16* wthi, f16* wtlo)
{
    __shared__ float t[64][65];
    const int bx = blockIdx.x & 15;        // n-tile (HIDN/64 = 16)
    const int by = blockIdx.x >> 4;        // k-tile (DIMK/64 = 64)
    #pragma unroll
    for (int i = 0; i < 16; ++i) {
        const int e = threadIdx.x + i * 256;
        const int r = e >> 6, c = e & 63;
        t[r][c] = w1[(size_t)(by * 64 + r) * HIDN + bx * 64 + c];
    }
    __syncthreads();
    #pragma unroll
    for (int i = 0; i < 16; ++i) {
        const int e = threadIdx.x + i * 256;
        const int nrow = e >> 6, kcol = e & 63;
        f16 h, l;
        split_f16(t[kcol][nrow], h, l);
        const size_t o = (size_t)(bx * 64 + nrow) * DIMK + by * 64 + kcol;
        wthi[o] = h;
        wtlo[o] = l;
    }
}

// ---------------------------------------------------------------------------
// Kernel C: 256x256-tile fused 3-term f16-split MFMA scorer.
//   acc += (xhi*2^11)*whi + xhi*wlo_s + xlo_s*whi    (all at 2^11 scale)
// A-side: x read fp32 DIRECTLY, pkrtz-split in registers, ds_write swizzled.
// B-side: wthi/wtlo via global_load_lds, pre-swizzled source.
// BK=32, 8 waves (2Mx4N), per-wave 128x64 out, acc[8][4] f32x4 (AGPRs).
// Double-buffered 2x64KB LDS; ONE barrier per K-tile; t+1 loads issued at
// top of tile t; 4 C-quadrant phases with setprio(1) around MFMA clusters.
// partials[slot][token], slot = nblk*4 + wc (16 slots), summed by router.
// ---------------------------------------------------------------------------
#define TBM 256
#define TBN 256
#define TBK 32
#define BUF_BYTES 65536   // Ahi@0(16K) Alo@16K Bhi@32K Blo@48K

__global__ __launch_bounds__(512, 2) void mod_mfma256_kernel(
    const float* x, const f16* wthi, const f16* wtlo,
    const float* b1, const float* w2, float* partials)
{
    __shared__ __align__(16) char lds[2 * BUF_BYTES];   // 128 KB

    const int tid  = threadIdx.x;
    const int lane = tid & 63;
    const int wid  = tid >> 6;
    const int wr   = wid >> 2;       // 0..1
    const int wc   = wid & 3;        // 0..3

    // XCD-chunked bijective swizzle: 256 blocks % 8 == 0
    const int bid  = blockIdx.x;
    const int v    = (bid & 7) * 32 + (bid >> 3);
    const int nblk = v & 3;          // 0..3
    const int mblk = v >> 2;         // 0..63
    const int tokBase = mblk * TBM;
    const int nBase   = nblk * TBN;

    // ---- A staging constants: pair p = tid + i*512: row=p>>2, kqq=p&3
    int arow[2], akqq[2], adst[2];
    #pragma unroll
    for (int i = 0; i < 2; ++i) {
        const int p = tid + i * 512;
        arow[i] = p >> 2;
        akqq[i] = p & 3;
        adst[i] = arow[i] * 64 + ((akqq[i] ^ ((arow[i] >> 1) & 3)) << 4);
    }
    // ---- B staging constants: 32 chunks of 1KB (16 rows x 64B)
    const f16* bsrcm[4];
    int bsrcoff[4], bdst[4];
    #pragma unroll
    for (int j = 0; j < 4; ++j) {
        const int c    = wid * 4 + j;            // 0..31
        const int half = c >> 4;                 // 0=hi 1=lo
        const int rloc = (c & 15) * 16 + (lane >> 2);
        bsrcm[j]   = half ? wtlo : wthi;
        bsrcoff[j] = (nBase + rloc) * (DIMK * 2) + (((lane & 3) << 4) ^ swzf(rloc));
        bdst[j]    = 32768 + half * 16384 + (c & 15) * 1024;
    }

    // ---- fragment read byte offsets (hi regions; lo = +16384)
    int aoff[8], boff[4];
    #pragma unroll
    for (int m = 0; m < 8; ++m) {
        const int r = wr * 128 + m * 16 + (lane & 15);
        aoff[m] = r * 64 + (((lane >> 4) ^ ((r >> 1) & 3)) << 4);
    }
    #pragma unroll
    for (int n = 0; n < 4; ++n) {
        const int c = wc * 64 + n * 16 + (lane & 15);
        boff[n] = 32768 + c * 64 + (((lane >> 4) ^ ((c >> 1) & 3)) << 4);
    }

    f32x4 acc[8][4];
    #pragma unroll
    for (int m = 0; m < 8; ++m)
        #pragma unroll
        for (int n = 0; n < 4; ++n)
            #pragma unroll
            for (int j = 0; j < 4; ++j) acc[m][n][j] = 0.0f;

    const f16 kS = (f16)LO_SCALE;

    // ---- prologue: stage tile 0 into buffer 0
    {
        float4 a0[2], a1[2];
        #pragma unroll
        for (int i = 0; i < 2; ++i) {
            const float* src = x + (size_t)(tokBase + arow[i]) * DIMK + akqq[i] * 8;
            a0[i] = *(const float4*)(src);
            a1[i] = *(const float4*)(src + 4);
        }
        #pragma unroll
        for (int j = 0; j < 4; ++j)
            load_lds16((const char*)bsrcm[j] + bsrcoff[j], lds + bdst[j]);
        #pragma unroll
        for (int i = 0; i < 2; ++i) {
            f16x8 h8, l8;
            split8(a0[i], a1[i], h8, l8);
            *(f16x8*)(lds + adst[i]) = h8;
            *(f16x8*)(lds + 16384 + adst[i]) = l8;
        }
        __syncthreads();
    }

    for (int t = 0; t < DIMK / TBK; ++t) {
        const int cur = (t & 1) * BUF_BYTES;
        const int nxt = BUF_BYTES - cur;
        const bool pf = (t + 1 < DIMK / TBK);
        const int k0n = (t + 1) * TBK;

        // [1] issue A fp32 loads for t+1 (to regs)
        float4 a0[2], a1[2];
        if (pf) {
            #pragma unroll
            for (int i = 0; i < 2; ++i) {
                const float* src = x + (size_t)(tokBase + arow[i]) * DIMK + k0n + akqq[i] * 8;
                a0[i] = *(const float4*)(src);
                a1[i] = *(const float4*)(src + 4);
            }
            // [2] issue B global_load_lds for t+1 into nxt
            #pragma unroll
            for (int j = 0; j < 4; ++j)
                load_lds16((const char*)bsrcm[j] + bsrcoff[j] + k0n * 2, lds + nxt + bdst[j]);
        }

        f16x8 afh[4], afl[4], bh0[2], bl0[2], bh1[2], bl1[2];
        // ---- phase (0,0): m 0..3 x n 0..1
        #pragma unroll
        for (int m = 0; m < 4; ++m) {
            afh[m] = *(const f16x8*)(lds + cur + aoff[m]);
            afl[m] = *(const f16x8*)(lds + cur + 16384 + aoff[m]);
        }
        #pragma unroll
        for (int n = 0; n < 2; ++n) {
            bh0[n] = *(const f16x8*)(lds + cur + boff[n]);
            bl0[n] = *(const f16x8*)(lds + cur + 16384 + boff[n]);
        }
        __builtin_amdgcn_s_setprio(1);
        #pragma unroll
        for (int m = 0; m < 4; ++m) {
            const f16x8 afs = afh[m] * kS;
            #pragma unroll
            for (int n = 0; n < 2; ++n) {
                acc[m][n] = mfma16(afs,    bh0[n], acc[m][n]);
                acc[m][n] = mfma16(afh[m], bl0[n], acc[m][n]);
                acc[m][n] = mfma16(afl[m], bh0[n], acc[m][n]);
            }
        }
        __builtin_amdgcn_s_setprio(0);
        // ---- phase (0,1): m 0..3 x n 2..3
        #pragma unroll
        for (int n = 0; n < 2; ++n) {
            bh1[n] = *(const f16x8*)(lds + cur + boff[2 + n]);
            bl1[n] = *(const f16x8*)(lds + cur + 16384 + boff[2 + n]);
        }
        __builtin_amdgcn_s_setprio(1);
        #pragma unroll
        for (int m = 0; m < 4; ++m) {
            const f16x8 afs = afh[m] * kS;
            #pragma unroll
            for (int n = 0; n < 2; ++n) {
                acc[m][2 + n] = mfma16(afs,    bh1[n], acc[m][2 + n]);
                acc[m][2 + n] = mfma16(afh[m], bl1[n], acc[m][2 + n]);
                acc[m][2 + n] = mfma16(afl[m], bh1[n], acc[m][2 + n]);
            }
        }
        __builtin_amdgcn_s_setprio(0);
        // [5] convert + ds_write A for t+1 (compiler inserts the vmcnt wait)
        if (pf) {
            #pragma unroll
            for (int i = 0; i < 2; ++i) {
                f16x8 h8, l8;
                split8(a0[i], a1[i], h8, l8);
                *(f16x8*)(lds + nxt + adst[i]) = h8;
                *(f16x8*)(lds + nxt + 16384 + adst[i]) = l8;
            }
        }
        // ---- phase (1,0): m 4..7 x n 0..1
        #pragma unroll
        for (int m = 0; m < 4; ++m) {
            afh[m] = *(const f16x8*)(lds + cur + aoff[4 + m]);
            afl[m] = *(const f16x8*)(lds + cur + 16384 + aoff[4 + m]);
        }
        __builtin_amdgcn_s_setprio(1);
        #pragma unroll
        for (int m = 0; m < 4; ++m) {
            const f16x8 afs = afh[m] * kS;
            #pragma unroll
            for (int n = 0; n < 2; ++n) {
                acc[4 + m][n] = mfma16(afs,    bh0[n], acc[4 + m][n]);
                acc[4 + m][n] = mfma16(afh[m], bl0[n], acc[4 + m][n]);
                acc[4 + m][n] = mfma16(afl[m], bh0[n], acc[4 + m][n]);
            }
        }
        __builtin_amdgcn_s_setprio(0);
        // ---- phase (1,1): m 4..7 x n 2..3
        __builtin_amdgcn_s_setprio(1);
        #pragma unroll
        for (int m = 0; m < 4; ++m) {
            const f16x8 afs = afh[m] * kS;
            #pragma unroll
            for (int n = 0; n < 2; ++n) {
                acc[4 + m][2 + n] = mfma16(afs,    bh1[n], acc[4 + m][2 + n]);
                acc[4 + m][2 + n] = mfma16(afh[m], bl1[n], acc[4 + m][2 + n]);
                acc[4 + m][2 + n] = mfma16(afl[m], bh1[n], acc[4 + m][2 + n]);
            }
        }
        __builtin_amdgcn_s_setprio(0);

        __syncthreads();   // one barrier per K-tile: cur reads done, nxt ready
    }

    // ---- epilogue: h = acc/2048 + b1; partial = sum relu(h)*w2 over 64 cols
    // C/D layout (m89): col = lane&15, row = (lane>>4)*4 + j per fragment.
    float rp[8][4];
    #pragma unroll
    for (int m = 0; m < 8; ++m)
        #pragma unroll
        for (int j = 0; j < 4; ++j) rp[m][j] = 0.0f;

    #pragma unroll
    for (int n = 0; n < 4; ++n) {
        const int col = nBase + wc * 64 + n * 16 + (lane & 15);
        const float wv = w2[col];
        const float bb = b1[col];
        #pragma unroll
        for (int m = 0; m < 8; ++m)
            #pragma unroll
            for (int j = 0; j < 4; ++j) {
                float h = fmaf(acc[m][n][j], INV_LO_SCALE, bb);
                h = fmaxf(h, 0.0f);
                rp[m][j] = fmaf(h, wv, rp[m][j]);
            }
    }
    #pragma unroll
    for (int off = 1; off < 16; off <<= 1)
        #pragma unroll
        for (int m = 0; m < 8; ++m)
            #pragma unroll
            for (int j = 0; j < 4; ++j)
                rp[m][j] += __shfl_xor(rp[m][j], off, 64);

    if ((lane & 15) == 0) {
        const int q = lane >> 4;
        const int slot = nblk * 4 + wc;
        float* pdst = partials + (size_t)slot * NTOK + tokBase + wr * 128 + q * 4;
        #pragma unroll
        for (int m = 0; m < 8; ++m)
            #pragma unroll
            for (int j = 0; j < 4; ++j)
                pdst[m * 16 + j] = rp[m][j];
    }
}

// ---------------------------------------------------------------------------
// Kernel D: router (validated semantics), scores = sum of 16 partials + b2.
// ---------------------------------------------------------------------------
__global__ __launch_bounds__(1024) void mod_route_part_kernel(
    const float* partials, const float* b2,
    float* mask_out, float* rw_out)
{
    __shared__ float s[SLEN];
    __shared__ int   sg[2][1024];
    __shared__ int   se[2][1024];
    __shared__ float red[1024];

    const int b   = blockIdx.x;
    const int tid = threadIdx.x;
    const int base = tid * 4;
    const float bias2 = b2[0];

    float og[4];
    #pragma unroll
    for (int u = 0; u < 4; ++u) {
        const size_t tok = (size_t)b * SLEN + base + u;
        float sum = bias2;
        #pragma unroll
        for (int p = 0; p < NPART; ++p) sum += partials[(size_t)p * NTOK + tok];
        og[u] = sum;
        s[base + u] = sum;
    }
    __syncthreads();

    for (int k = 2; k <= SLEN; k <<= 1) {
        for (int j = k >> 1; j > 0; j >>= 1) {
            for (int i = tid; i < SLEN; i += 1024) {
                const int ixj = i ^ j;
                if (ixj > i) {
                    const float a = s[i];
                    const float c = s[ixj];
                    const bool descRegion = ((i & k) == 0);
                    if (descRegion ? (a < c) : (a > c)) { s[i] = c; s[ixj] = a; }
                }
            }
            __syncthreads();
        }
    }

    const float maxv      = s[0];
    const float threshold = s[KSEL - 1];

    float part = 0.f;
    for (int i = tid; i < KSEL; i += 1024) part += expf(s[i] - maxv);
    red[tid] = part;
    __syncthreads();
    for (int off = 512; off > 0; off >>= 1) {
        if (tid < off) red[tid] += red[tid + off];
        __syncthreads();
    }
    const float sumexp = red[0];
    __syncthreads();

    int gcnt = 0, ecnt = 0;
    #pragma unroll
    for (int u = 0; u < 4; ++u) {
        gcnt += (og[u] > threshold);
        ecnt += (og[u] == threshold);
    }

    int cur = 0;
    sg[0][tid] = gcnt;
    se[0][tid] = ecnt;
    __syncthreads();
    for (int off = 1; off < 1024; off <<= 1) {
        const int nxt = cur ^ 1;
        int vg = sg[cur][tid];
        int ve = se[cur][tid];
        if (tid >= off) { vg += sg[cur][tid - off]; ve += se[cur][tid - off]; }
        sg[nxt][tid] = vg;
        se[nxt][tid] = ve;
        __syncthreads();
        cur = nxt;
    }
    const int total_gt = sg[cur][1023];
    const int R = KSEL - total_gt;
    int pgi = sg[cur][tid] - gcnt;
    int pei = se[cur][tid] - ecnt;

    const float inv_sum = 1.0f / sumexp;
    #pragma unroll
    for (int u = 0; u < 4; ++u) {
        const bool isg = og[u] > threshold;
        const bool ise = og[u] == threshold;
        const bool sel = isg || (ise && pei < R);
        float rwv = 0.f;
        if (sel) {
            const int rank = pgi + (pei < R ? pei : R);
            rwv = expf(s[rank] - maxv) * inv_sum;
        }
        const size_t oi = (size_t)b * SLEN + base + u;
        mask_out[oi] = sel ? 1.0f : 0.0f;
        rw_out[oi]   = rwv;
        pgi += isg;
        pei += ise;
    }
}

// ---------------------------------------------------------------------------
// Fallback path (ws too small): validated fp32 VALU scorer + router
// ---------------------------------------------------------------------------
#define BM 64
#define BN 256
#define BK 32
#define THREADS 512

__global__ __launch_bounds__(THREADS) void mod_score_kernel(
    const float* x, const float* w1, const float* b1,
    const float* w2, const float* b2, float* scores)
{
    __shared__ float Xs[BK][BM + 4];
    __shared__ float Ws[BK][BN];

    const int tid = threadIdx.x;
    const int tx = tid & 31;
    const int ty = tid >> 5;
    const int tokBase = blockIdx.x * BM;

    float sp[4] = {0.f, 0.f, 0.f, 0.f};
    const float bias2 = b2[0];

    for (int hc = 0; hc < HIDN; hc += BN) {
        float acc[4][8];
        #pragma unroll
        for (int m = 0; m < 4; ++m)
            #pragma unroll
            for (int n = 0; n < 8; ++n) acc[m][n] = 0.f;

        for (int k0 = 0; k0 < DIMK; k0 += BK) {
            {
                const int r  = tid >> 3;
                const int c4 = tid & 7;
                const float4 vv = *(const float4*)(x + (size_t)(tokBase + r) * DIMK + k0 + c4 * 4);
                Xs[c4 * 4 + 0][r] = vv.x;
                Xs[c4 * 4 + 1][r] = vv.y;
                Xs[c4 * 4 + 2][r] = vv.z;
                Xs[c4 * 4 + 3][r] = vv.w;
            }
            #pragma unroll
            for (int i = 0; i < 4; ++i) {
                const int idx = tid + i * THREADS;
                const int r   = idx >> 6;
                const int c4  = idx & 63;
                const float4 vv = *(const float4*)(w1 + (size_t)(k0 + r) * HIDN + hc + c4 * 4);
                *(float4*)&Ws[r][c4 * 4] = vv;
            }
            __syncthreads();

            #pragma unroll 8
            for (int k = 0; k < BK; ++k) {
                const float4 xv = *(const float4*)&Xs[k][ty * 4];
                const float4 wa = *(const float4*)&Ws[k][tx * 4];
                const float4 wb = *(const float4*)&Ws[k][128 + tx * 4];
                const float xm[4] = {xv.x, xv.y, xv.z, xv.w};
                const float wn[8] = {wa.x, wa.y, wa.z, wa.w, wb.x, wb.y, wb.z, wb.w};
                #pragma unroll
                for (int m = 0; m < 4; ++m)
                    #pragma unroll
                    for (int n = 0; n < 8; ++n)
                        acc[m][n] = fmaf(xm[m], wn[n], acc[m][n]);
            }
            __syncthreads();
        }

        #pragma unroll
        for (int half = 0; half < 2; ++half) {
            #pragma unroll
            for (int n = 0; n < 4; ++n) {
                const int h = hc + half * 128 + tx * 4 + n;
                const float wv = w2[h];
                const float bb = b1[h];
                #pragma unroll
                for (int m = 0; m < 4; ++m) {
                    float hv = acc[m][half * 4 + n] + bb;
                    hv = fmaxf(hv, 0.f);
                    sp[m] = fmaf(hv, wv, sp[m]);
                }
            }
        }
    }

    #pragma unroll
    for (int off = 1; off < 32; off <<= 1) {
        #pragma unroll
        for (int m = 0; m < 4; ++m) sp[m] += __shfl_xor(sp[m], off, 64);
    }
    if (tx == 0) {
        #pragma unroll
        for (int m = 0; m < 4; ++m)
            scores[tokBase + ty * 4 + m] = sp[m] + bias2;
    }
}

__global__ __launch_bounds__(1024) void mod_route_kernel(
    const float* scores, float* mask_out, float* rw_out)
{
    __shared__ float s[SLEN];
    __shared__ int   sg[2][1024];
    __shared__ int   se[2][1024];
    __shared__ float red[1024];

    const int b   = blockIdx.x;
    const int tid = threadIdx.x;
    const float* rowp = scores + (size_t)b * SLEN;
    const int base = tid * 4;

    const float4 ov = *(const float4*)(rowp + base);
    float og[4] = {ov.x, ov.y, ov.z, ov.w};
    s[base + 0] = ov.x;
    s[base + 1] = ov.y;
    s[base + 2] = ov.z;
    s[base + 3] = ov.w;
    __syncthreads();

    for (int k = 2; k <= SLEN; k <<= 1) {
        for (int j = k >> 1; j > 0; j >>= 1) {
            for (int i = tid; i < SLEN; i += 1024) {
                const int ixj = i ^ j;
                if (ixj > i) {
                    const float a = s[i];
                    const float c = s[ixj];
                    const bool descRegion = ((i & k) == 0);
                    if (descRegion ? (a < c) : (a > c)) { s[i] = c; s[ixj] = a; }
                }
            }
            __syncthreads();
        }
    }

    const float maxv      = s[0];
    const float threshold = s[KSEL - 1];

    float part = 0.f;
    for (int i = tid; i < KSEL; i += 1024) part += expf(s[i] - maxv);
    red[tid] = part;
    __syncthreads();
    for (int off = 512; off > 0; off >>= 1) {
        if (tid < off) red[tid] += red[tid + off];
        __syncthreads();
    }
    const float sumexp = red[0];
    __syncthreads();

    int gcnt = 0, ecnt = 0;
    #pragma unroll
    for (int u = 0; u < 4; ++u) {
        gcnt += (og[u] > threshold);
        ecnt += (og[u] == threshold);
    }

    int cur = 0;
    sg[0][tid] = gcnt;
    se[0][tid] = ecnt;
    __syncthreads();
    for (int off = 1; off < 1024; off <<= 1) {
        const int nxt = cur ^ 1;
        int vg = sg[cur][tid];
        int ve = se[cur][tid];
        if (tid >= off) { vg += sg[cur][tid - off]; ve += se[cur][tid - off]; }
        sg[nxt][tid] = vg;
        se[nxt][tid] = ve;
        __syncthreads();
        cur = nxt;
    }
    const int total_gt = sg[cur][1023];
    const int R = KSEL - total_gt;
    int pgi = sg[cur][tid] - gcnt;
    int pei = se[cur][tid] - ecnt;

    const float inv_sum = 1.0f / sumexp;
    #pragma unroll
    for (int u = 0; u < 4; ++u) {
        const bool isg = og[u] > threshold;
        const bool ise = og[u] == threshold;
        const bool sel = isg || (ise && pei < R);
        float rwv = 0.f;
        if (sel) {
            const int rank = pgi + (pei < R ? pei : R);
            rwv = expf(s[rank] - maxv) * inv_sum;
        }
        const size_t oi = (size_t)b * SLEN + base + u;
        mask_out[oi] = sel ? 1.0f : 0.0f;
        rw_out[oi]   = rwv;
        pgi += isg;
        pei += ise;
    }
}

// ---------------------------------------------------------------------------
extern "C" void kernel_launch(void* const* d_in, const int* in_sizes, int n_in,
                              void* d_out, int out_size, void* d_ws, size_t ws_size,
                              hipStream_t stream) {
    const float* x  = (const float*)d_in[0];
    const float* w1 = (const float*)d_in[1];
    const float* b1 = (const float*)d_in[2];
    const float* w2 = (const float*)d_in[3];
    const float* b2 = (const float*)d_in[4];

    float* out      = (float*)d_out;
    float* mask_out = out;            // [4, 4096]
    float* rw_out   = out + NTOK;     // [4, 4096]

    const size_t partials_b = (size_t)NPART * NTOK * 4;          // 1 MB
    const size_t wsplit_b   = (size_t)HIDN * DIMK * 2;           // 8 MB each
    const size_t needed     = partials_b + 2 * wsplit_b;         // 17 MB

    if (ws_size >= needed) {
        char* wsb = (char*)d_ws;
        float* partials = (float*)wsb;
        f16* wthi = (f16*)(wsb + partials_b);
        f16* wtlo = wthi + (size_t)HIDN * DIMK;

        conv_w1_kernel<<<1024, 256, 0, stream>>>(w1, wthi, wtlo);
        mod_mfma256_kernel<<<256, 512, 0, stream>>>(x, wthi, wtlo, b1, w2, partials);
        mod_route_part_kernel<<<NBATCH, 1024, 0, stream>>>(partials, b2, mask_out, rw_out);
    } else {
        float* scores = (ws_size >= (size_t)NTOK * sizeof(float)) ? (float*)d_ws : rw_out;
        mod_score_kernel<<<NTOK / BM, THREADS, 0, stream>>>(x, w1, b1, w2, b2, scores);
        mod_route_kernel<<<NBATCH, 1024, 0, stream>>>(scores, mask_out, rw_out);
    }
}

// Round 9
// 399.142 us; speedup vs baseline: 1.9724x; 1.0072x over previous
//
#include <hip/hip_runtime.h>
#include <math.h>

typedef _Float16 f16;
typedef _Float16 f16x8 __attribute__((ext_vector_type(8)));
typedef float    f32x4 __attribute__((ext_vector_type(4)));

#define DIMK 4096
#define HIDN 1024
#define NTOK 16384
#define SLEN 4096
#define NBATCH 4
#define KSEL 2048
#define NPART 16

#define LO_SCALE 2048.0f              // 2^11
#define INV_ACC_SCALE (1.0f/4194304.0f)  // 2^-22

// ---------------------------------------------------------------------------
// helpers
// ---------------------------------------------------------------------------
__device__ __forceinline__ void load_lds16(const void* g, void* l) {
    __builtin_amdgcn_global_load_lds(
        (const __attribute__((address_space(1))) unsigned int*)g,
        (__attribute__((address_space(3))) unsigned int*)l, 16, 0, 0);
}
// XOR swizzle of the 16B slot index within a 64B LDS row (2-way-max banks).
__device__ __forceinline__ int swzf(int row) { return ((row >> 1) & 3) << 4; }

// w1 split, PRE-SCALED by 2^11 on BOTH planes (uniform-2^22 scheme):
//   hi_s = ((f16)v) * 2^11   (exact pow2; always f16-normal => no MFMA flush,
//                             the old subnormal clamp is unnecessary)
//   lo_s = (v - (f16)v) * 2^11
__device__ __forceinline__ void split_w(float v, f16& hi_s, f16& lo_s) {
    const f16 h = (f16)v;
    const float hf = (float)h;
    hi_s = (f16)(hf * LO_SCALE);
    lo_s = (f16)((v - hf) * LO_SCALE);
}

// Fast packed split for x (hot path), pre-scaled by 2^11:
//   vs = v*2048 (exact);  h_s = pkrtz(vs);  l_s = pkrtz(vs - h_s)
// vs - h_s is exact in fp32 (Sterbenz); values identical to the validated
// round-8 split times 2^11. RTZ rounding is absorbed exactly by l_s.
__device__ __forceinline__ void split8(const float4 v0, const float4 v1,
                                       f16x8& h8, f16x8& l8) {
    const float s0 = v0.x * LO_SCALE, s1 = v0.y * LO_SCALE;
    const float s2 = v0.z * LO_SCALE, s3 = v0.w * LO_SCALE;
    const float s4 = v1.x * LO_SCALE, s5 = v1.y * LO_SCALE;
    const float s6 = v1.z * LO_SCALE, s7 = v1.w * LO_SCALE;
    const auto h01 = __builtin_amdgcn_cvt_pkrtz(s0, s1);
    const auto h23 = __builtin_amdgcn_cvt_pkrtz(s2, s3);
    const auto h45 = __builtin_amdgcn_cvt_pkrtz(s4, s5);
    const auto h67 = __builtin_amdgcn_cvt_pkrtz(s6, s7);
    const auto l01 = __builtin_amdgcn_cvt_pkrtz(s0 - (float)h01[0], s1 - (float)h01[1]);
    const auto l23 = __builtin_amdgcn_cvt_pkrtz(s2 - (float)h23[0], s3 - (float)h23[1]);
    const auto l45 = __builtin_amdgcn_cvt_pkrtz(s4 - (float)h45[0], s5 - (float)h45[1]);
    const auto l67 = __builtin_amdgcn_cvt_pkrtz(s6 - (float)h67[0], s7 - (float)h67[1]);
    h8 = f16x8{(f16)h01[0], (f16)h01[1], (f16)h23[0], (f16)h23[1],
               (f16)h45[0], (f16)h45[1], (f16)h67[0], (f16)h67[1]};
    l8 = f16x8{(f16)l01[0], (f16)l01[1], (f16)l23[0], (f16)l23[1],
               (f16)l45[0], (f16)l45[1], (f16)l67[0], (f16)l67[1]};
}

__device__ __forceinline__ f32x4 mfma16(f16x8 a, f16x8 b, f32x4 c) {
    return __builtin_amdgcn_mfma_f32_16x16x32_f16(a, b, c, 0, 0, 0);
}

// ---------------------------------------------------------------------------
// Kernel B: transpose + convert w1 [DIMK][HIDN] fp32 -> w1t hi_s/lo_s
// [HIDN][DIMK] f16, both planes pre-scaled by 2^11.
// ---------------------------------------------------------------------------
__global__ __launch_bounds__(256) void conv_w1_kernel(
    const float* w1, f16* wthi, f16* wtlo)
{
    __shared__ float t[64][65];
    const int bx = blockIdx.x & 15;        // n-tile (HIDN/64 = 16)
    const int by = blockIdx.x >> 4;        // k-tile (DIMK/64 = 64)
    #pragma unroll
    for (int i = 0; i < 16; ++i) {
        const int e = threadIdx.x + i * 256;
        const int r = e >> 6, c = e & 63;
        t[r][c] = w1[(size_t)(by * 64 + r) * HIDN + bx * 64 + c];
    }
    __syncthreads();
    #pragma unroll
    for (int i = 0; i < 16; ++i) {
        const int e = threadIdx.x + i * 256;
        const int nrow = e >> 6, kcol = e & 63;
        f16 h, l;
        split_w(t[kcol][nrow], h, l);
        const size_t o = (size_t)(bx * 64 + nrow) * DIMK + by * 64 + kcol;
        wthi[o] = h;
        wtlo[o] = l;
    }
}

// ---------------------------------------------------------------------------
// Kernel C: 256x256-tile fused 3-term f16-split MFMA scorer, uniform 2^22:
//   acc = (xhi_s*whi_s + xhi_s*wlo_s + xlo_s*whi_s) = (x@w1)*2^22 + eps
// ZERO in-loop VALU scaling (the old afs=afh*2048 per-phase rescale is gone).
// A-side: x read fp32 DIRECTLY, pkrtz-split in registers, ds_write swizzled.
// B-side: wthi/wtlo via global_load_lds, pre-swizzled source.
// BK=32, 8 waves (2Mx4N), per-wave 128x64 out, acc[8][4] f32x4 (AGPRs).
// Double-buffered 2x64KB LDS; ONE barrier per K-tile; t+1 loads issued at
// top of tile t; 4 C-quadrant phases with setprio(1) around MFMA clusters.
// partials[slot][token], slot = nblk*4 + wc (16 slots), summed by router.
// ---------------------------------------------------------------------------
#define TBM 256
#define TBN 256
#define TBK 32
#define BUF_BYTES 65536   // Ahi@0(16K) Alo@16K Bhi@32K Blo@48K

__global__ __launch_bounds__(512, 2) void mod_mfma256_kernel(
    const float* x, const f16* wthi, const f16* wtlo,
    const float* b1, const float* w2, float* partials)
{
    __shared__ __align__(16) char lds[2 * BUF_BYTES];   // 128 KB

    const int tid  = threadIdx.x;
    const int lane = tid & 63;
    const int wid  = tid >> 6;
    const int wr   = wid >> 2;       // 0..1
    const int wc   = wid & 3;        // 0..3

    // XCD-chunked bijective swizzle: 256 blocks % 8 == 0
    const int bid  = blockIdx.x;
    const int v    = (bid & 7) * 32 + (bid >> 3);
    const int nblk = v & 3;          // 0..3
    const int mblk = v >> 2;         // 0..63
    const int tokBase = mblk * TBM;
    const int nBase   = nblk * TBN;

    // ---- A staging constants: pair p = tid + i*512: row=p>>2, kqq=p&3
    int arow[2], akqq[2], adst[2];
    #pragma unroll
    for (int i = 0; i < 2; ++i) {
        const int p = tid + i * 512;
        arow[i] = p >> 2;
        akqq[i] = p & 3;
        adst[i] = arow[i] * 64 + ((akqq[i] ^ ((arow[i] >> 1) & 3)) << 4);
    }
    // ---- B staging constants: 32 chunks of 1KB (16 rows x 64B)
    const f16* bsrcm[4];
    int bsrcoff[4], bdst[4];
    #pragma unroll
    for (int j = 0; j < 4; ++j) {
        const int c    = wid * 4 + j;            // 0..31
        const int half = c >> 4;                 // 0=hi 1=lo
        const int rloc = (c & 15) * 16 + (lane >> 2);
        bsrcm[j]   = half ? wtlo : wthi;
        bsrcoff[j] = (nBase + rloc) * (DIMK * 2) + (((lane & 3) << 4) ^ swzf(rloc));
        bdst[j]    = 32768 + half * 16384 + (c & 15) * 1024;
    }

    // ---- fragment read byte offsets (hi regions; lo = +16384)
    int aoff[8], boff[4];
    #pragma unroll
    for (int m = 0; m < 8; ++m) {
        const int r = wr * 128 + m * 16 + (lane & 15);
        aoff[m] = r * 64 + (((lane >> 4) ^ ((r >> 1) & 3)) << 4);
    }
    #pragma unroll
    for (int n = 0; n < 4; ++n) {
        const int c = wc * 64 + n * 16 + (lane & 15);
        boff[n] = 32768 + c * 64 + (((lane >> 4) ^ ((c >> 1) & 3)) << 4);
    }

    f32x4 acc[8][4];
    #pragma unroll
    for (int m = 0; m < 8; ++m)
        #pragma unroll
        for (int n = 0; n < 4; ++n)
            #pragma unroll
            for (int j = 0; j < 4; ++j) acc[m][n][j] = 0.0f;

    // ---- prologue: stage tile 0 into buffer 0
    {
        float4 a0[2], a1[2];
        #pragma unroll
        for (int i = 0; i < 2; ++i) {
            const float* src = x + (size_t)(tokBase + arow[i]) * DIMK + akqq[i] * 8;
            a0[i] = *(const float4*)(src);
            a1[i] = *(const float4*)(src + 4);
        }
        #pragma unroll
        for (int j = 0; j < 4; ++j)
            load_lds16((const char*)bsrcm[j] + bsrcoff[j], lds + bdst[j]);
        #pragma unroll
        for (int i = 0; i < 2; ++i) {
            f16x8 h8, l8;
            split8(a0[i], a1[i], h8, l8);
            *(f16x8*)(lds + adst[i]) = h8;
            *(f16x8*)(lds + 16384 + adst[i]) = l8;
        }
        __syncthreads();
    }

    for (int t = 0; t < DIMK / TBK; ++t) {
        const int cur = (t & 1) * BUF_BYTES;
        const int nxt = BUF_BYTES - cur;
        const bool pf = (t + 1 < DIMK / TBK);
        const int k0n = (t + 1) * TBK;

        // [1] issue A fp32 loads for t+1 (to regs)
        float4 a0[2], a1[2];
        if (pf) {
            #pragma unroll
            for (int i = 0; i < 2; ++i) {
                const float* src = x + (size_t)(tokBase + arow[i]) * DIMK + k0n + akqq[i] * 8;
                a0[i] = *(const float4*)(src);
                a1[i] = *(const float4*)(src + 4);
            }
            // [2] issue B global_load_lds for t+1 into nxt
            #pragma unroll
            for (int j = 0; j < 4; ++j)
                load_lds16((const char*)bsrcm[j] + bsrcoff[j] + k0n * 2, lds + nxt + bdst[j]);
        }

        f16x8 afh[4], afl[4], bh0[2], bl0[2], bh1[2], bl1[2];
        // ---- phase (0,0): m 0..3 x n 0..1
        #pragma unroll
        for (int m = 0; m < 4; ++m) {
            afh[m] = *(const f16x8*)(lds + cur + aoff[m]);
            afl[m] = *(const f16x8*)(lds + cur + 16384 + aoff[m]);
        }
        #pragma unroll
        for (int n = 0; n < 2; ++n) {
            bh0[n] = *(const f16x8*)(lds + cur + boff[n]);
            bl0[n] = *(const f16x8*)(lds + cur + 16384 + boff[n]);
        }
        __builtin_amdgcn_s_setprio(1);
        #pragma unroll
        for (int m = 0; m < 4; ++m)
            #pragma unroll
            for (int n = 0; n < 2; ++n) {
                acc[m][n] = mfma16(afh[m], bh0[n], acc[m][n]);
                acc[m][n] = mfma16(afh[m], bl0[n], acc[m][n]);
                acc[m][n] = mfma16(afl[m], bh0[n], acc[m][n]);
            }
        __builtin_amdgcn_s_setprio(0);
        // ---- phase (0,1): m 0..3 x n 2..3
        #pragma unroll
        for (int n = 0; n < 2; ++n) {
            bh1[n] = *(const f16x8*)(lds + cur + boff[2 + n]);
            bl1[n] = *(const f16x8*)(lds + cur + 16384 + boff[2 + n]);
        }
        __builtin_amdgcn_s_setprio(1);
        #pragma unroll
        for (int m = 0; m < 4; ++m)
            #pragma unroll
            for (int n = 0; n < 2; ++n) {
                acc[m][2 + n] = mfma16(afh[m], bh1[n], acc[m][2 + n]);
                acc[m][2 + n] = mfma16(afh[m], bl1[n], acc[m][2 + n]);
                acc[m][2 + n] = mfma16(afl[m], bh1[n], acc[m][2 + n]);
            }
        __builtin_amdgcn_s_setprio(0);
        // [5] convert + ds_write A for t+1 (compiler inserts the vmcnt wait)
        if (pf) {
            #pragma unroll
            for (int i = 0; i < 2; ++i) {
                f16x8 h8, l8;
                split8(a0[i], a1[i], h8, l8);
                *(f16x8*)(lds + nxt + adst[i]) = h8;
                *(f16x8*)(lds + nxt + 16384 + adst[i]) = l8;
            }
        }
        // ---- phase (1,0): m 4..7 x n 0..1
        #pragma unroll
        for (int m = 0; m < 4; ++m) {
            afh[m] = *(const f16x8*)(lds + cur + aoff[4 + m]);
            afl[m] = *(const f16x8*)(lds + cur + 16384 + aoff[4 + m]);
        }
        __builtin_amdgcn_s_setprio(1);
        #pragma unroll
        for (int m = 0; m < 4; ++m)
            #pragma unroll
            for (int n = 0; n < 2; ++n) {
                acc[4 + m][n] = mfma16(afh[m], bh0[n], acc[4 + m][n]);
                acc[4 + m][n] = mfma16(afh[m], bl0[n], acc[4 + m][n]);
                acc[4 + m][n] = mfma16(afl[m], bh0[n], acc[4 + m][n]);
            }
        __builtin_amdgcn_s_setprio(0);
        // ---- phase (1,1): m 4..7 x n 2..3
        __builtin_amdgcn_s_setprio(1);
        #pragma unroll
        for (int m = 0; m < 4; ++m)
            #pragma unroll
            for (int n = 0; n < 2; ++n) {
                acc[4 + m][2 + n] = mfma16(afh[m], bh1[n], acc[4 + m][2 + n]);
                acc[4 + m][2 + n] = mfma16(afh[m], bl1[n], acc[4 + m][2 + n]);
                acc[4 + m][2 + n] = mfma16(afl[m], bh1[n], acc[4 + m][2 + n]);
            }
        __builtin_amdgcn_s_setprio(0);

        __syncthreads();   // one barrier per K-tile: cur reads done, nxt ready
    }

    // ---- epilogue: h = acc*2^-22 + b1; partial = sum relu(h)*w2 over 64 cols
    // C/D layout (m89): col = lane&15, row = (lane>>4)*4 + j per fragment.
    float rp[8][4];
    #pragma unroll
    for (int m = 0; m < 8; ++m)
        #pragma unroll
        for (int j = 0; j < 4; ++j) rp[m][j] = 0.0f;

    #pragma unroll
    for (int n = 0; n < 4; ++n) {
        const int col = nBase + wc * 64 + n * 16 + (lane & 15);
        const float wv = w2[col];
        const float bb = b1[col];
        #pragma unroll
        for (int m = 0; m < 8; ++m)
            #pragma unroll
            for (int j = 0; j < 4; ++j) {
                float h = fmaf(acc[m][n][j], INV_ACC_SCALE, bb);
                h = fmaxf(h, 0.0f);
                rp[m][j] = fmaf(h, wv, rp[m][j]);
            }
    }
    #pragma unroll
    for (int off = 1; off < 16; off <<= 1)
        #pragma unroll
        for (int m = 0; m < 8; ++m)
            #pragma unroll
            for (int j = 0; j < 4; ++j)
                rp[m][j] += __shfl_xor(rp[m][j], off, 64);

    if ((lane & 15) == 0) {
        const int q = lane >> 4;
        const int slot = nblk * 4 + wc;
        float* pdst = partials + (size_t)slot * NTOK + tokBase + wr * 128 + q * 4;
        #pragma unroll
        for (int m = 0; m < 8; ++m)
            #pragma unroll
            for (int j = 0; j < 4; ++j)
                pdst[m * 16 + j] = rp[m][j];
    }
}

// ---------------------------------------------------------------------------
// Kernel D: router (validated semantics), scores = sum of 16 partials + b2.
// ---------------------------------------------------------------------------
__global__ __launch_bounds__(1024) void mod_route_part_kernel(
    const float* partials, const float* b2,
    float* mask_out, float* rw_out)
{
    __shared__ float s[SLEN];
    __shared__ int   sg[2][1024];
    __shared__ int   se[2][1024];
    __shared__ float red[1024];

    const int b   = blockIdx.x;
    const int tid = threadIdx.x;
    const int base = tid * 4;
    const float bias2 = b2[0];

    float og[4];
    #pragma unroll
    for (int u = 0; u < 4; ++u) {
        const size_t tok = (size_t)b * SLEN + base + u;
        float sum = bias2;
        #pragma unroll
        for (int p = 0; p < NPART; ++p) sum += partials[(size_t)p * NTOK + tok];
        og[u] = sum;
        s[base + u] = sum;
    }
    __syncthreads();

    for (int k = 2; k <= SLEN; k <<= 1) {
        for (int j = k >> 1; j > 0; j >>= 1) {
            for (int i = tid; i < SLEN; i += 1024) {
                const int ixj = i ^ j;
                if (ixj > i) {
                    const float a = s[i];
                    const float c = s[ixj];
                    const bool descRegion = ((i & k) == 0);
                    if (descRegion ? (a < c) : (a > c)) { s[i] = c; s[ixj] = a; }
                }
            }
            __syncthreads();
        }
    }

    const float maxv      = s[0];
    const float threshold = s[KSEL - 1];

    float part = 0.f;
    for (int i = tid; i < KSEL; i += 1024) part += expf(s[i] - maxv);
    red[tid] = part;
    __syncthreads();
    for (int off = 512; off > 0; off >>= 1) {
        if (tid < off) red[tid] += red[tid + off];
        __syncthreads();
    }
    const float sumexp = red[0];
    __syncthreads();

    int gcnt = 0, ecnt = 0;
    #pragma unroll
    for (int u = 0; u < 4; ++u) {
        gcnt += (og[u] > threshold);
        ecnt += (og[u] == threshold);
    }

    int cur = 0;
    sg[0][tid] = gcnt;
    se[0][tid] = ecnt;
    __syncthreads();
    for (int off = 1; off < 1024; off <<= 1) {
        const int nxt = cur ^ 1;
        int vg = sg[cur][tid];
        int ve = se[cur][tid];
        if (tid >= off) { vg += sg[cur][tid - off]; ve += se[cur][tid - off]; }
        sg[nxt][tid] = vg;
        se[nxt][tid] = ve;
        __syncthreads();
        cur = nxt;
    }
    const int total_gt = sg[cur][1023];
    const int R = KSEL - total_gt;
    int pgi = sg[cur][tid] - gcnt;
    int pei = se[cur][tid] - ecnt;

    const float inv_sum = 1.0f / sumexp;
    #pragma unroll
    for (int u = 0; u < 4; ++u) {
        const bool isg = og[u] > threshold;
        const bool ise = og[u] == threshold;
        const bool sel = isg || (ise && pei < R);
        float rwv = 0.f;
        if (sel) {
            const int rank = pgi + (pei < R ? pei : R);
            rwv = expf(s[rank] - maxv) * inv_sum;
        }
        const size_t oi = (size_t)b * SLEN + base + u;
        mask_out[oi] = sel ? 1.0f : 0.0f;
        rw_out[oi]   = rwv;
        pgi += isg;
        pei += ise;
    }
}

// ---------------------------------------------------------------------------
// Fallback path (ws too small): validated fp32 VALU scorer + router
// ---------------------------------------------------------------------------
#define BM 64
#define BN 256
#define BK 32
#define THREADS 512

__global__ __launch_bounds__(THREADS) void mod_score_kernel(
    const float* x, const float* w1, const float* b1,
    const float* w2, const float* b2, float* scores)
{
    __shared__ float Xs[BK][BM + 4];
    __shared__ float Ws[BK][BN];

    const int tid = threadIdx.x;
    const int tx = tid & 31;
    const int ty = tid >> 5;
    const int tokBase = blockIdx.x * BM;

    float sp[4] = {0.f, 0.f, 0.f, 0.f};
    const float bias2 = b2[0];

    for (int hc = 0; hc < HIDN; hc += BN) {
        float acc[4][8];
        #pragma unroll
        for (int m = 0; m < 4; ++m)
            #pragma unroll
            for (int n = 0; n < 8; ++n) acc[m][n] = 0.f;

        for (int k0 = 0; k0 < DIMK; k0 += BK) {
            {
                const int r  = tid >> 3;
                const int c4 = tid & 7;
                const float4 vv = *(const float4*)(x + (size_t)(tokBase + r) * DIMK + k0 + c4 * 4);
                Xs[c4 * 4 + 0][r] = vv.x;
                Xs[c4 * 4 + 1][r] = vv.y;
                Xs[c4 * 4 + 2][r] = vv.z;
                Xs[c4 * 4 + 3][r] = vv.w;
            }
            #pragma unroll
            for (int i = 0; i < 4; ++i) {
                const int idx = tid + i * THREADS;
                const int r   = idx >> 6;
                const int c4  = idx & 63;
                const float4 vv = *(const float4*)(w1 + (size_t)(k0 + r) * HIDN + hc + c4 * 4);
                *(float4*)&Ws[r][c4 * 4] = vv;
            }
            __syncthreads();

            #pragma unroll 8
            for (int k = 0; k < BK; ++k) {
                const float4 xv = *(const float4*)&Xs[k][ty * 4];
                const float4 wa = *(const float4*)&Ws[k][tx * 4];
                const float4 wb = *(const float4*)&Ws[k][128 + tx * 4];
                const float xm[4] = {xv.x, xv.y, xv.z, xv.w};
                const float wn[8] = {wa.x, wa.y, wa.z, wa.w, wb.x, wb.y, wb.z, wb.w};
                #pragma unroll
                for (int m = 0; m < 4; ++m)
                    #pragma unroll
                    for (int n = 0; n < 8; ++n)
                        acc[m][n] = fmaf(xm[m], wn[n], acc[m][n]);
            }
            __syncthreads();
        }

        #pragma unroll
        for (int half = 0; half < 2; ++half) {
            #pragma unroll
            for (int n = 0; n < 4; ++n) {
                const int h = hc + half * 128 + tx * 4 + n;
                const float wv = w2[h];
                const float bb = b1[h];
                #pragma unroll
                for (int m = 0; m < 4; ++m) {
                    float hv = acc[m][half * 4 + n] + bb;
                    hv = fmaxf(hv, 0.f);
                    sp[m] = fmaf(hv, wv, sp[m]);
                }
            }
        }
    }

    #pragma unroll
    for (int off = 1; off < 32; off <<= 1) {
        #pragma unroll
        for (int m = 0; m < 4; ++m) sp[m] += __shfl_xor(sp[m], off, 64);
    }
    if (tx == 0) {
        #pragma unroll
        for (int m = 0; m < 4; ++m)
            scores[tokBase + ty * 4 + m] = sp[m] + bias2;
    }
}

__global__ __launch_bounds__(1024) void mod_route_kernel(
    const float* scores, float* mask_out, float* rw_out)
{
    __shared__ float s[SLEN];
    __shared__ int   sg[2][1024];
    __shared__ int   se[2][1024];
    __shared__ float red[1024];

    const int b   = blockIdx.x;
    const int tid = threadIdx.x;
    const float* rowp = scores + (size_t)b * SLEN;
    const int base = tid * 4;

    const float4 ov = *(const float4*)(rowp + base);
    float og[4] = {ov.x, ov.y, ov.z, ov.w};
    s[base + 0] = ov.x;
    s[base + 1] = ov.y;
    s[base + 2] = ov.z;
    s[base + 3] = ov.w;
    __syncthreads();

    for (int k = 2; k <= SLEN; k <<= 1) {
        for (int j = k >> 1; j > 0; j >>= 1) {
            for (int i = tid; i < SLEN; i += 1024) {
                const int ixj = i ^ j;
                if (ixj > i) {
                    const float a = s[i];
                    const float c = s[ixj];
                    const bool descRegion = ((i & k) == 0);
                    if (descRegion ? (a < c) : (a > c)) { s[i] = c; s[ixj] = a; }
                }
            }
            __syncthreads();
        }
    }

    const float maxv      = s[0];
    const float threshold = s[KSEL - 1];

    float part = 0.f;
    for (int i = tid; i < KSEL; i += 1024) part += expf(s[i] - maxv);
    red[tid] = part;
    __syncthreads();
    for (int off = 512; off > 0; off >>= 1) {
        if (tid < off) red[tid] += red[tid + off];
        __syncthreads();
    }
    const float sumexp = red[0];
    __syncthreads();

    int gcnt = 0, ecnt = 0;
    #pragma unroll
    for (int u = 0; u < 4; ++u) {
        gcnt += (og[u] > threshold);
        ecnt += (og[u] == threshold);
    }

    int cur = 0;
    sg[0][tid] = gcnt;
    se[0][tid] = ecnt;
    __syncthreads();
    for (int off = 1; off < 1024; off <<= 1) {
        const int nxt = cur ^ 1;
        int vg = sg[cur][tid];
        int ve = se[cur][tid];
        if (tid >= off) { vg += sg[cur][tid - off]; ve += se[cur][tid - off]; }
        sg[nxt][tid] = vg;
        se[nxt][tid] = ve;
        __syncthreads();
        cur = nxt;
    }
    const int total_gt = sg[cur][1023];
    const int R = KSEL - total_gt;
    int pgi = sg[cur][tid] - gcnt;
    int pei = se[cur][tid] - ecnt;

    const float inv_sum = 1.0f / sumexp;
    #pragma unroll
    for (int u = 0; u < 4; ++u) {
        const bool isg = og[u] > threshold;
        const bool ise = og[u] == threshold;
        const bool sel = isg || (ise && pei < R);
        float rwv = 0.f;
        if (sel) {
            const int rank = pgi + (pei < R ? pei : R);
            rwv = expf(s[rank] - maxv) * inv_sum;
        }
        const size_t oi = (size_t)b * SLEN + base + u;
        mask_out[oi] = sel ? 1.0f : 0.0f;
        rw_out[oi]   = rwv;
        pgi += isg;
        pei += ise;
    }
}

// ---------------------------------------------------------------------------
extern "C" void kernel_launch(void* const* d_in, const int* in_sizes, int n_in,
                              void* d_out, int out_size, void* d_ws, size_t ws_size,
                              hipStream_t stream) {
    const float* x  = (const float*)d_in[0];
    const float* w1 = (const float*)d_in[1];
    const float* b1 = (const float*)d_in[2];
    const float* w2 = (const float*)d_in[3];
    const float* b2 = (const float*)d_in[4];

    float* out      = (float*)d_out;
    float* mask_out = out;            // [4, 4096]
    float* rw_out   = out + NTOK;     // [4, 4096]

    const size_t partials_b = (size_t)NPART * NTOK * 4;          // 1 MB
    const size_t wsplit_b   = (size_t)HIDN * DIMK * 2;           // 8 MB each
    const size_t needed     = partials_b + 2 * wsplit_b;         // 17 MB

    if (ws_size >= needed) {
        char* wsb = (char*)d_ws;
        float* partials = (float*)wsb;
        f16* wthi = (f16*)(wsb + partials_b);
        f16* wtlo = wthi + (size_t)HIDN * DIMK;

        conv_w1_kernel<<<1024, 256, 0, stream>>>(w1, wthi, wtlo);
        mod_mfma256_kernel<<<256, 512, 0, stream>>>(x, wthi, wtlo, b1, w2, partials);
        mod_route_part_kernel<<<NBATCH, 1024, 0, stream>>>(partials, b2, mask_out, rw_out);
    } else {
        float* scores = (ws_size >= (size_t)NTOK * sizeof(float)) ? (float*)d_ws : rw_out;
        mod_score_kernel<<<NTOK / BM, THREADS, 0, stream>>>(x, w1, b1, w2, b2, scores);
        mod_route_kernel<<<NBATCH, 1024, 0, stream>>>(scores, mask_out, rw_out);
    }
}